// Round 1
// baseline (1388.870 us; speedup 1.0000x reference)
//
#include <hip/hip_runtime.h>
#include <math.h>

#define D_ 128
#define NH_ 8
#define G_ 2048
#define B_ 4
#define KEEP_ 512
#define NENC_ 513
#define HID_ 512
#define EPS_ 1e-5f

// ---------------------------------------------------------------------------
// Stable rank of noise within each batch row.
// rank == ids_restore; mask = (rank >= KEEP); keep_ids[rank] = i for rank<KEEP
// ---------------------------------------------------------------------------
__global__ void rank_kernel(const float* __restrict__ noise, int* __restrict__ rank,
                            int* __restrict__ keep_ids, float* __restrict__ mask_out) {
    int b = blockIdx.y;
    int i = blockIdx.x * 256 + threadIdx.x;
    __shared__ float sn[G_];
    const float* row = noise + (size_t)b * G_;
    for (int j = threadIdx.x; j < G_; j += 256) sn[j] = row[j];
    __syncthreads();
    float vi = sn[i];
    int r = 0;
    for (int j = 0; j < G_; ++j) {
        float vj = sn[j];
        r += (vj < vi) || (vj == vi && j < i);
    }
    rank[b * G_ + i] = r;
    mask_out[b * G_ + i] = (r >= KEEP_) ? 1.0f : 0.0f;
    if (r < KEEP_) keep_ids[b * KEEP_ + r] = i;
}

// ---------------------------------------------------------------------------
// h[b,0,:] = cls ; h[b,1+k,:] = x[b,ik]*ew + eb + pos[ik]
// ---------------------------------------------------------------------------
__global__ void embed_gather_kernel(const float* __restrict__ x, const float* __restrict__ pos,
                                    const float* __restrict__ cls, const float* __restrict__ ew,
                                    const float* __restrict__ eb, const int* __restrict__ keep_ids,
                                    float* __restrict__ h) {
    int n = blockIdx.x;          // 0..NENC-1
    int b = blockIdx.y;
    int d = threadIdx.x;         // 0..127
    float v;
    if (n == 0) {
        v = cls[d];
    } else {
        int i = keep_ids[b * KEEP_ + (n - 1)];
        v = x[b * G_ + i] * ew[d] + eb[d] + pos[(size_t)i * D_ + d];
    }
    h[((size_t)b * NENC_ + n) * D_ + d] = v;
}

// ---------------------------------------------------------------------------
// Row LayerNorm, D=128, one row per 128-thread block (2 waves)
// ---------------------------------------------------------------------------
__global__ void ln_kernel(const float* __restrict__ in, float* __restrict__ out,
                          const float* __restrict__ g, const float* __restrict__ bta) {
    int row = blockIdx.x;
    int t = threadIdx.x;
    float v = in[(size_t)row * D_ + t];
    float s = v;
    #pragma unroll
    for (int o = 1; o < 64; o <<= 1) s += __shfl_xor(s, o);
    __shared__ float ss[2];
    __shared__ float qq[2];
    if ((t & 63) == 0) ss[t >> 6] = s;
    __syncthreads();
    float mu = (ss[0] + ss[1]) * (1.0f / D_);
    float dv = v - mu;
    float q = dv * dv;
    #pragma unroll
    for (int o = 1; o < 64; o <<= 1) q += __shfl_xor(q, o);
    if ((t & 63) == 0) qq[t >> 6] = q;
    __syncthreads();
    float var = (qq[0] + qq[1]) * (1.0f / D_);
    out[(size_t)row * D_ + t] = dv * rsqrtf(var + EPS_) * g[t] + bta[t];
}

// ---------------------------------------------------------------------------
// C = A(MxK) @ W(KxN) + bias, epilogue mode: 0=none, 1=gelu(exact), 2=+R
// 64x64 tile, 256 threads, 4x4 per thread, K-step 16. N%64==0, K%16==0.
// ---------------------------------------------------------------------------
__global__ __launch_bounds__(256) void gemm_kernel(
    const float* __restrict__ A, const float* __restrict__ W,
    const float* __restrict__ bias, const float* __restrict__ R,
    float* __restrict__ C, int M, int K, int N, int mode) {
    __shared__ float As[16][68];
    __shared__ float Bs[16][68];
    int tid = threadIdx.x;
    int tx = tid & 15, ty = tid >> 4;
    int bm = blockIdx.x * 64, bn = blockIdx.y * 64;
    int arow = tid >> 2, akq = (tid & 3) * 4;     // A tile: 64 rows x 16 k
    int brow = tid >> 4, bnq = (tid & 15) * 4;    // B tile: 16 k x 64 n
    float acc[4][4] = {};
    for (int k0 = 0; k0 < K; k0 += 16) {
        float4 av = make_float4(0.f, 0.f, 0.f, 0.f);
        if (bm + arow < M)
            av = *(const float4*)(A + (size_t)(bm + arow) * K + k0 + akq);
        float4 bv = *(const float4*)(W + (size_t)(k0 + brow) * N + bn + bnq);
        __syncthreads();
        As[akq + 0][arow] = av.x; As[akq + 1][arow] = av.y;
        As[akq + 2][arow] = av.z; As[akq + 3][arow] = av.w;
        *(float4*)&Bs[brow][bnq] = bv;
        __syncthreads();
        #pragma unroll
        for (int k = 0; k < 16; ++k) {
            float4 a4 = *(const float4*)&As[k][ty * 4];
            float4 b4 = *(const float4*)&Bs[k][tx * 4];
            float a[4] = {a4.x, a4.y, a4.z, a4.w};
            float bb[4] = {b4.x, b4.y, b4.z, b4.w};
            #pragma unroll
            for (int i = 0; i < 4; ++i)
                #pragma unroll
                for (int j = 0; j < 4; ++j) acc[i][j] += a[i] * bb[j];
        }
    }
    #pragma unroll
    for (int i = 0; i < 4; ++i) {
        int mrow = bm + ty * 4 + i;
        if (mrow >= M) continue;
        #pragma unroll
        for (int j = 0; j < 4; ++j) {
            int ncol = bn + tx * 4 + j;
            float v = acc[i][j] + bias[ncol];
            if (mode == 1) v = 0.5f * v * (1.0f + erff(v * 0.70710678118654752f));
            else if (mode == 2) v += R[(size_t)mrow * N + ncol];
            C[(size_t)mrow * N + ncol] = v;
        }
    }
}

// ---------------------------------------------------------------------------
// Flash attention, fp32. qkv layout per row: [s*128 + h*16 + e], s in {q,k,v}.
// Block: 64 q-rows, 256 threads: tx(16) over k, ty(16) over q(4 rows each).
// grid (ceil(N/64), NH, B). out[b,n, h*16+e] (row-major M x 128).
// ---------------------------------------------------------------------------
__global__ __launch_bounds__(256) void attn_kernel(
    const float* __restrict__ qkv, float* __restrict__ out, int N) {
    int qt = blockIdx.x, h = blockIdx.y, b = blockIdx.z;
    int tid = threadIdx.x;
    int tx = tid & 15, ty = tid >> 4;
    const float* base = qkv + (size_t)b * N * 384;
    __shared__ float Ks[64][17];
    __shared__ float Vs[64][17];
    float q[4][16];
    int q0 = qt * 64 + ty * 4;
    #pragma unroll
    for (int i = 0; i < 4; ++i) {
        int qi = q0 + i;
        if (qi < N) {
            const float* qp = base + (size_t)qi * 384 + h * 16;
            #pragma unroll
            for (int e = 0; e < 16; ++e) q[i][e] = qp[e] * 0.25f;  // hd^-0.5
        } else {
            #pragma unroll
            for (int e = 0; e < 16; ++e) q[i][e] = 0.f;
        }
    }
    float m[4], l[4], acc[4][16];
    #pragma unroll
    for (int i = 0; i < 4; ++i) {
        m[i] = -1e30f; l[i] = 0.f;
        #pragma unroll
        for (int e = 0; e < 16; ++e) acc[i][e] = 0.f;
    }
    int sn = tid >> 2, se = (tid & 3) * 4;
    int nkt = (N + 63) >> 6;
    for (int kt = 0; kt < nkt; ++kt) {
        int ng = kt * 64 + sn;
        float4 kv = make_float4(0.f, 0.f, 0.f, 0.f);
        float4 vv = make_float4(0.f, 0.f, 0.f, 0.f);
        if (ng < N) {
            kv = *(const float4*)(base + (size_t)ng * 384 + 128 + h * 16 + se);
            vv = *(const float4*)(base + (size_t)ng * 384 + 256 + h * 16 + se);
        }
        __syncthreads();
        Ks[sn][se + 0] = kv.x; Ks[sn][se + 1] = kv.y; Ks[sn][se + 2] = kv.z; Ks[sn][se + 3] = kv.w;
        Vs[sn][se + 0] = vv.x; Vs[sn][se + 1] = vv.y; Vs[sn][se + 2] = vv.z; Vs[sn][se + 3] = vv.w;
        __syncthreads();
        int kvalid = N - kt * 64;
        float sc[4][4];
        #pragma unroll
        for (int i = 0; i < 4; ++i)
            #pragma unroll
            for (int j = 0; j < 4; ++j) sc[i][j] = 0.f;
        #pragma unroll
        for (int e = 0; e < 16; ++e) {
            float kvv[4];
            #pragma unroll
            for (int j = 0; j < 4; ++j) kvv[j] = Ks[tx * 4 + j][e];
            #pragma unroll
            for (int i = 0; i < 4; ++i)
                #pragma unroll
                for (int j = 0; j < 4; ++j) sc[i][j] += q[i][e] * kvv[j];
        }
        #pragma unroll
        for (int j = 0; j < 4; ++j) {
            if (tx * 4 + j >= kvalid) {
                #pragma unroll
                for (int i = 0; i < 4; ++i) sc[i][j] = -1e30f;
            }
        }
        #pragma unroll
        for (int i = 0; i < 4; ++i) {
            float tmax = fmaxf(fmaxf(sc[i][0], sc[i][1]), fmaxf(sc[i][2], sc[i][3]));
            tmax = fmaxf(tmax, __shfl_xor(tmax, 1));
            tmax = fmaxf(tmax, __shfl_xor(tmax, 2));
            tmax = fmaxf(tmax, __shfl_xor(tmax, 4));
            tmax = fmaxf(tmax, __shfl_xor(tmax, 8));
            float nm = fmaxf(m[i], tmax);
            float f = __expf(m[i] - nm);
            m[i] = nm;
            l[i] *= f;
            #pragma unroll
            for (int e = 0; e < 16; ++e) acc[i][e] *= f;
            float p[4];
            float ls = 0.f;
            #pragma unroll
            for (int j = 0; j < 4; ++j) { p[j] = __expf(sc[i][j] - nm); ls += p[j]; }
            l[i] += ls;
            #pragma unroll
            for (int j = 0; j < 4; ++j)
                #pragma unroll
                for (int e = 0; e < 16; ++e) acc[i][e] += p[j] * Vs[tx * 4 + j][e];
        }
    }
    // reduce over the 16 tx lanes (lane bits 0..3, same wave)
    #pragma unroll
    for (int i = 0; i < 4; ++i) {
        #pragma unroll
        for (int s = 1; s < 16; s <<= 1) l[i] += __shfl_xor(l[i], s);
        #pragma unroll
        for (int e = 0; e < 16; ++e) {
            #pragma unroll
            for (int s = 1; s < 16; s <<= 1) acc[i][e] += __shfl_xor(acc[i][e], s);
        }
    }
    __syncthreads();
    float* ylds = &Ks[0][0];  // reuse: 64*16 floats
    if (tx == 0) {
        #pragma unroll
        for (int i = 0; i < 4; ++i) {
            float inv = 1.0f / l[i];
            #pragma unroll
            for (int e = 0; e < 16; ++e) ylds[(ty * 4 + i) * 16 + e] = acc[i][e] * inv;
        }
    }
    __syncthreads();
    #pragma unroll
    for (int it = 0; it < 4; ++it) {
        int idx = tid + it * 256;
        int row = idx >> 4, e = idx & 15;
        int qi = qt * 64 + row;
        if (qi < N) out[((size_t)b * N + qi) * D_ + h * 16 + e] = ylds[row * 16 + e];
    }
}

// ---------------------------------------------------------------------------
// Decoder input: dembed rows 1+rank (if kept) or mask_token, + pos
// ---------------------------------------------------------------------------
__global__ void dec_build_kernel(const float* __restrict__ dembed, const float* __restrict__ mask_token,
                                 const float* __restrict__ pos, const int* __restrict__ rank,
                                 float* __restrict__ outp) {
    int i = blockIdx.x;      // 0..G-1
    int b = blockIdx.y;
    int d = threadIdx.x;
    int r = rank[b * G_ + i];
    float v = (r < KEEP_) ? dembed[((size_t)b * NENC_ + 1 + r) * D_ + d] : mask_token[d];
    outp[((size_t)b * G_ + i) * D_ + d] = v + pos[(size_t)i * D_ + d];
}

__global__ void cls_copy_kernel(const float* __restrict__ latent, float* __restrict__ outc) {
    int t = blockIdx.x * 128 + threadIdx.x;   // 0..511
    int b = t >> 7, d = t & 127;
    outc[t] = latent[(size_t)b * NENC_ * D_ + d];
}

// ---------------------------------------------------------------------------
// pred[row] = dot128(dln_row, pw) + pb; per-block masked sq-err partial sums
// ---------------------------------------------------------------------------
__global__ void pred_loss_kernel(const float* __restrict__ dln, const float* __restrict__ pw,
                                 const float* __restrict__ pb, const float* __restrict__ x,
                                 const int* __restrict__ rank,
                                 float* __restrict__ pred_out, float* __restrict__ bsums) {
    int tid = threadIdx.x;
    int wave = tid >> 6, lane = tid & 63;
    int row = blockIdx.x * 4 + wave;          // 0..8191
    const float* rp = dln + (size_t)row * D_;
    float s = rp[lane] * pw[lane] + rp[lane + 64] * pw[lane + 64];
    #pragma unroll
    for (int o = 1; o < 64; o <<= 1) s += __shfl_xor(s, o);
    __shared__ float ps[4];
    if (lane == 0) {
        float pred = s + pb[0];
        pred_out[row] = pred;
        float diff = pred - x[row];
        float msk = (rank[row] >= KEEP_) ? 1.0f : 0.0f;
        ps[wave] = diff * diff * msk;
    }
    __syncthreads();
    if (tid == 0) bsums[blockIdx.x] = ps[0] + ps[1] + ps[2] + ps[3];
}

__global__ void loss_fin_kernel(const float* __restrict__ bs, float* __restrict__ out0) {
    int t = threadIdx.x;  // 256
    float s = 0.f;
    for (int i = t; i < 2048; i += 256) s += bs[i];
    #pragma unroll
    for (int o = 1; o < 64; o <<= 1) s += __shfl_xor(s, o);
    __shared__ float ps[4];
    if ((t & 63) == 0) ps[t >> 6] = s;
    __syncthreads();
    if (t == 0) out0[0] = (ps[0] + ps[1] + ps[2] + ps[3]) * (1.0f / 6144.0f);
}

// ---------------------------------------------------------------------------
extern "C" void kernel_launch(void* const* d_in, const int* in_sizes, int n_in,
                              void* d_out, int out_size, void* d_ws, size_t ws_size,
                              hipStream_t stream) {
    const float* x     = (const float*)d_in[0];
    const float* noise = (const float*)d_in[1];
    const float* pos   = (const float*)d_in[2];
    const float* cls   = (const float*)d_in[3];
    const float* eew   = (const float*)d_in[4];
    const float* eeb   = (const float*)d_in[5];
    const float* nw    = (const float*)d_in[6];
    const float* nb    = (const float*)d_in[7];
    const float* dew   = (const float*)d_in[8];
    const float* deb   = (const float*)d_in[9];
    const float* mtok  = (const float*)d_in[10];
    const float* dnw   = (const float*)d_in[11];
    const float* dnb   = (const float*)d_in[12];
    const float* pw    = (const float*)d_in[13];
    const float* pb    = (const float*)d_in[14];
    const float* eln1w = (const float*)d_in[15];
    const float* eln1b = (const float*)d_in[16];
    const float* eqkvw = (const float*)d_in[17];
    const float* eqkvb = (const float*)d_in[18];
    const float* eprjw = (const float*)d_in[19];
    const float* eprjb = (const float*)d_in[20];
    const float* eln2w = (const float*)d_in[21];
    const float* eln2b = (const float*)d_in[22];
    const float* ef1w  = (const float*)d_in[23];
    const float* ef1b  = (const float*)d_in[24];
    const float* ef2w  = (const float*)d_in[25];
    const float* ef2b  = (const float*)d_in[26];
    const float* dln1w = (const float*)d_in[27];
    const float* dln1b = (const float*)d_in[28];
    const float* dqkvw = (const float*)d_in[29];
    const float* dqkvb = (const float*)d_in[30];
    const float* dprjw = (const float*)d_in[31];
    const float* dprjb = (const float*)d_in[32];
    const float* dln2w = (const float*)d_in[33];
    const float* dln2b = (const float*)d_in[34];
    const float* df1w  = (const float*)d_in[35];
    const float* df1b  = (const float*)d_in[36];
    const float* df2w  = (const float*)d_in[37];
    const float* df2b  = (const float*)d_in[38];

    char* ws = (char*)d_ws;
    int*   rank   = (int*)(ws + 0);            // 32768 B
    int*   keep   = (int*)(ws + 32768);        // 8192 B
    float* bsums  = (float*)(ws + 40960);      // 8192 B
    float* enc_x  = (float*)(ws + 49152);      // 1050624 B (B*513*128)
    float* lnbuf  = (float*)(ws + 1099776);    // 4194304 B (B*2048*128)
    float* attnb  = (float*)(ws + 5294080);    // 4194304 B
    float* qbuf   = (float*)(ws + 9488384);    // 16777216 B (qkv / mlp-hid, aliased)
    float* latent = (float*)(ws + 26265600);   // 1050624 B
    float* demb   = (float*)(ws + 27316224);   // 1050624 B
    float* decx   = (float*)(ws + 28366848);   // 4194304 B  -> total ~32.6 MB

    float* outp = (float*)d_out;
    float* pred_out = outp + 1;
    float* mask_out = outp + 1 + B_ * G_;
    float* cls_out  = outp + 1 + 2 * B_ * G_;

    // ---- masking / shuffle ----
    rank_kernel<<<dim3(G_ / 256, B_), 256, 0, stream>>>(noise, rank, keep, mask_out);
    embed_gather_kernel<<<dim3(NENC_, B_), 128, 0, stream>>>(x, pos, cls, eew, eeb, keep, enc_x);

    // ---- encoder ----
    const int Menc = B_ * NENC_;               // 2052
    const int gmE = (Menc + 63) / 64;          // 33
    for (int L = 0; L < 6; ++L) {
        ln_kernel<<<Menc, 128, 0, stream>>>(enc_x, lnbuf, eln1w + L * D_, eln1b + L * D_);
        gemm_kernel<<<dim3(gmE, 6), 256, 0, stream>>>(lnbuf, eqkvw + (size_t)L * D_ * 384,
                                                      eqkvb + L * 384, nullptr, qbuf, Menc, 128, 384, 0);
        attn_kernel<<<dim3((NENC_ + 63) / 64, NH_, B_), 256, 0, stream>>>(qbuf, attnb, NENC_);
        gemm_kernel<<<dim3(gmE, 2), 256, 0, stream>>>(attnb, eprjw + (size_t)L * D_ * D_,
                                                      eprjb + L * D_, enc_x, enc_x, Menc, 128, 128, 2);
        ln_kernel<<<Menc, 128, 0, stream>>>(enc_x, lnbuf, eln2w + L * D_, eln2b + L * D_);
        gemm_kernel<<<dim3(gmE, 8), 256, 0, stream>>>(lnbuf, ef1w + (size_t)L * D_ * HID_,
                                                      ef1b + L * HID_, nullptr, qbuf, Menc, 128, 512, 1);
        gemm_kernel<<<dim3(gmE, 2), 256, 0, stream>>>(qbuf, ef2w + (size_t)L * HID_ * D_,
                                                      ef2b + L * D_, enc_x, enc_x, Menc, 512, 128, 2);
    }
    ln_kernel<<<Menc, 128, 0, stream>>>(enc_x, latent, nw, nb);
    cls_copy_kernel<<<4, 128, 0, stream>>>(latent, cls_out);

    // ---- decoder embed + unshuffle ----
    gemm_kernel<<<dim3(gmE, 2), 256, 0, stream>>>(latent, dew, deb, nullptr, demb, Menc, 128, 128, 0);
    dec_build_kernel<<<dim3(G_, B_), 128, 0, stream>>>(demb, mtok, pos, rank, decx);

    // ---- decoder ----
    const int Mdec = B_ * G_;                  // 8192
    const int gmD = Mdec / 64;                 // 128
    for (int L = 0; L < 2; ++L) {
        ln_kernel<<<Mdec, 128, 0, stream>>>(decx, lnbuf, dln1w + L * D_, dln1b + L * D_);
        gemm_kernel<<<dim3(gmD, 6), 256, 0, stream>>>(lnbuf, dqkvw + (size_t)L * D_ * 384,
                                                      dqkvb + L * 384, nullptr, qbuf, Mdec, 128, 384, 0);
        attn_kernel<<<dim3(G_ / 64, NH_, B_), 256, 0, stream>>>(qbuf, attnb, G_);
        gemm_kernel<<<dim3(gmD, 2), 256, 0, stream>>>(attnb, dprjw + (size_t)L * D_ * D_,
                                                      dprjb + L * D_, decx, decx, Mdec, 128, 128, 2);
        ln_kernel<<<Mdec, 128, 0, stream>>>(decx, lnbuf, dln2w + L * D_, dln2b + L * D_);
        gemm_kernel<<<dim3(gmD, 8), 256, 0, stream>>>(lnbuf, df1w + (size_t)L * D_ * HID_,
                                                      df1b + L * HID_, nullptr, qbuf, Mdec, 128, 512, 1);
        gemm_kernel<<<dim3(gmD, 2), 256, 0, stream>>>(qbuf, df2w + (size_t)L * HID_ * D_,
                                                      df2b + L * D_, decx, decx, Mdec, 512, 128, 2);
    }
    ln_kernel<<<Mdec, 128, 0, stream>>>(decx, lnbuf, dnw, dnb);

    // ---- prediction + loss ----
    pred_loss_kernel<<<Mdec / 4, 256, 0, stream>>>(lnbuf, pw, pb, x, rank, pred_out, bsums);
    loss_fin_kernel<<<1, 256, 0, stream>>>(bsums, outp);
}

// Round 2
// 1254.404 us; speedup vs baseline: 1.1072x; 1.1072x over previous
//
#include <hip/hip_runtime.h>
#include <math.h>

#define D_ 128
#define NH_ 8
#define G_ 2048
#define B_ 4
#define KEEP_ 512
#define NENC_ 513
#define HID_ 512
#define EPS_ 1e-5f

typedef short bf16x8 __attribute__((ext_vector_type(8)));
typedef float f32x4 __attribute__((ext_vector_type(4)));

static __device__ __forceinline__ float b2f(short s) {
    union { float f; unsigned u; } v;
    v.u = ((unsigned)(unsigned short)s) << 16;
    return v.f;
}
static __device__ __forceinline__ short f2b(float f) {
    union { float f; unsigned u; } v;
    v.f = f;
    unsigned r = v.u + 0x7fffu + ((v.u >> 16) & 1u);   // RNE
    return (short)(r >> 16);
}

// ---------------------------------------------------------------------------
// Stable rank of noise within each batch row.
// ---------------------------------------------------------------------------
__global__ void rank_kernel(const float* __restrict__ noise, int* __restrict__ rank,
                            int* __restrict__ keep_ids, float* __restrict__ mask_out) {
    int b = blockIdx.y;
    int i = blockIdx.x * 256 + threadIdx.x;
    __shared__ float sn[G_];
    const float* row = noise + (size_t)b * G_;
    for (int j = threadIdx.x; j < G_; j += 256) sn[j] = row[j];
    __syncthreads();
    float vi = sn[i];
    int r = 0;
    for (int j = 0; j < G_; ++j) {
        float vj = sn[j];
        r += (vj < vi) || (vj == vi && j < i);
    }
    rank[b * G_ + i] = r;
    mask_out[b * G_ + i] = (r >= KEEP_) ? 1.0f : 0.0f;
    if (r < KEEP_) keep_ids[b * KEEP_ + r] = i;
}

// ---------------------------------------------------------------------------
__global__ void embed_gather_kernel(const float* __restrict__ x, const float* __restrict__ pos,
                                    const float* __restrict__ cls, const float* __restrict__ ew,
                                    const float* __restrict__ eb, const int* __restrict__ keep_ids,
                                    float* __restrict__ h) {
    int n = blockIdx.x, b = blockIdx.y;
    int d = threadIdx.x;
    float v;
    if (n == 0) v = cls[d];
    else {
        int i = keep_ids[b * KEEP_ + (n - 1)];
        v = x[b * G_ + i] * ew[d] + eb[d] + pos[(size_t)i * D_ + d];
    }
    h[((size_t)b * NENC_ + n) * D_ + d] = v;
}

// ---------------------------------------------------------------------------
// Weight transpose + bf16 cast: src (L,K,N) f32 -> dst (L,N,K) bf16
// ---------------------------------------------------------------------------
__global__ void wtrans_kernel(const float* __restrict__ src, short* __restrict__ dst,
                              int K, int N) {
    int l = blockIdx.z;
    __shared__ float t[32][33];
    int n0 = blockIdx.x * 32, k0 = blockIdx.y * 32;
    const float* s = src + (size_t)l * K * N;
    short* d = dst + (size_t)l * N * K;
    int tx = threadIdx.x & 31, ty = threadIdx.x >> 5;   // 256 thr: ty 0..7
    #pragma unroll
    for (int i = 0; i < 32; i += 8)
        t[ty + i][tx] = s[(size_t)(k0 + ty + i) * N + n0 + tx];
    __syncthreads();
    #pragma unroll
    for (int i = 0; i < 32; i += 8)
        d[(size_t)(n0 + ty + i) * K + k0 + tx] = f2b(t[tx][ty + i]);
}

// ---------------------------------------------------------------------------
// LayerNorm, fp32 in -> bf16 out
// ---------------------------------------------------------------------------
__global__ void ln_kernel(const float* __restrict__ in, short* __restrict__ out,
                          const float* __restrict__ g, const float* __restrict__ bta) {
    int row = blockIdx.x;
    int t = threadIdx.x;
    float v = in[(size_t)row * D_ + t];
    float s = v;
    #pragma unroll
    for (int o = 1; o < 64; o <<= 1) s += __shfl_xor(s, o);
    __shared__ float ss[2];
    __shared__ float qq[2];
    if ((t & 63) == 0) ss[t >> 6] = s;
    __syncthreads();
    float mu = (ss[0] + ss[1]) * (1.0f / D_);
    float dv = v - mu;
    float q = dv * dv;
    #pragma unroll
    for (int o = 1; o < 64; o <<= 1) q += __shfl_xor(q, o);
    if ((t & 63) == 0) qq[t >> 6] = q;
    __syncthreads();
    float var = (qq[0] + qq[1]) * (1.0f / D_);
    out[(size_t)row * D_ + t] = f2b(dv * rsqrtf(var + EPS_) * g[t] + bta[t]);
}

// ---------------------------------------------------------------------------
// bf16 MFMA GEMM: C = A(MxK bf16) @ W(KxN) + bias.  Wt = W^T (N x K, bf16).
// 128x128 tile, BK=64, 4 waves (2x2), 16x16x32 MFMA, XOR-bit4 LDS swizzle
// via pre-swizzled global source.  A buffer must be padded to 128-row mult.
// MODE: 0 fp32 out, 1 gelu->bf16, 2 +R fp32 out, 3 bf16 out
// ---------------------------------------------------------------------------
template<int MODE>
__global__ __launch_bounds__(256) void gemm_mfma_kernel(
    const short* __restrict__ A, const short* __restrict__ Wt,
    const float* __restrict__ bias, const float* __restrict__ R,
    void* __restrict__ Cout, int M, int K, int N) {
    __shared__ short As[128 * 64];
    __shared__ short Bs[128 * 64];
    int tid = threadIdx.x;
    int lane = tid & 63, wid = tid >> 6;
    int wr = wid >> 1, wc = wid & 1;
    int bm = blockIdx.x * 128, bn = blockIdx.y * 128;
    int l15 = lane & 15, lhi = lane >> 4;
    f32x4 acc[4][4];
    #pragma unroll
    for (int m = 0; m < 4; ++m)
        #pragma unroll
        for (int n = 0; n < 4; ++n) acc[m][n] = f32x4{0.f, 0.f, 0.f, 0.f};

    const char* Ab = (const char*)A;
    const char* Bb = (const char*)Wt;
    char* AsB = (char*)As;
    char* BsB = (char*)Bs;
    int p = tid * 16;
    int r0 = p >> 7, cb0 = p & 127;

    for (int k0 = 0; k0 < K; k0 += 64) {
        __syncthreads();
        #pragma unroll
        for (int it = 0; it < 4; ++it) {
            int r = r0 + it * 32;
            int scb = cb0 ^ ((r & 7) << 4);
            __builtin_amdgcn_global_load_lds(
                (const __attribute__((address_space(1))) void*)(Ab + (((size_t)(bm + r) * K + k0) << 1) + scb),
                (__attribute__((address_space(3))) void*)(AsB + it * 4096 + (wid << 10)), 16, 0, 0);
            __builtin_amdgcn_global_load_lds(
                (const __attribute__((address_space(1))) void*)(Bb + (((size_t)(bn + r) * K + k0) << 1) + scb),
                (__attribute__((address_space(3))) void*)(BsB + it * 4096 + (wid << 10)), 16, 0, 0);
        }
        asm volatile("s_waitcnt vmcnt(0)" ::: "memory");
        __syncthreads();
        #pragma unroll
        for (int kk = 0; kk < 2; ++kk) {
            bf16x8 a[4], b[4];
            int cbb = kk * 64 + lhi * 16;
            #pragma unroll
            for (int m = 0; m < 4; ++m) {
                int row = wr * 64 + m * 16 + l15;
                a[m] = *(const bf16x8*)(AsB + row * 128 + (cbb ^ ((row & 7) << 4)));
                int rowb = wc * 64 + m * 16 + l15;
                b[m] = *(const bf16x8*)(BsB + rowb * 128 + (cbb ^ ((rowb & 7) << 4)));
            }
            #pragma unroll
            for (int m = 0; m < 4; ++m)
                #pragma unroll
                for (int n = 0; n < 4; ++n)
                    acc[m][n] = __builtin_amdgcn_mfma_f32_16x16x32_bf16(a[m], b[n], acc[m][n], 0, 0, 0);
        }
    }
    // epilogue: C row = (lane>>4)*4+j, col = lane&15 within each 16x16 frag
    #pragma unroll
    for (int m = 0; m < 4; ++m) {
        int rbase = bm + wr * 64 + m * 16 + lhi * 4;
        #pragma unroll
        for (int n = 0; n < 4; ++n) {
            int col = bn + wc * 64 + n * 16 + l15;
            float bv = bias[col];
            #pragma unroll
            for (int j = 0; j < 4; ++j) {
                int rr = rbase + j;
                if (rr < M) {
                    float v = acc[m][n][j] + bv;
                    if (MODE == 1) {
                        v = 0.5f * v * (1.0f + erff(v * 0.70710678118654752f));
                        ((short*)Cout)[(size_t)rr * N + col] = f2b(v);
                    } else if (MODE == 2) {
                        ((float*)Cout)[(size_t)rr * N + col] = v + R[(size_t)rr * N + col];
                    } else if (MODE == 3) {
                        ((short*)Cout)[(size_t)rr * N + col] = f2b(v);
                    } else {
                        ((float*)Cout)[(size_t)rr * N + col] = v;
                    }
                }
            }
        }
    }
}

// ---------------------------------------------------------------------------
// Flash attention, fp32 math, bf16 qkv in / bf16 out.
// qkv row layout: [s*128 + h*16 + e].  grid (ceil(N/64), NH, B), 256 thr.
// ---------------------------------------------------------------------------
__global__ __launch_bounds__(256) void attn_kernel(
    const short* __restrict__ qkv, short* __restrict__ out, int N) {
    int qt = blockIdx.x, h = blockIdx.y, b = blockIdx.z;
    int tid = threadIdx.x;
    int tx = tid & 15, ty = tid >> 4;
    const short* base = qkv + (size_t)b * N * 384;
    __shared__ float Ks[64][17];
    __shared__ float Vs[64][17];
    float q[4][16];
    int q0 = qt * 64 + ty * 4;
    #pragma unroll
    for (int i = 0; i < 4; ++i) {
        int qi = q0 + i;
        if (qi < N) {
            const short* qp = base + (size_t)qi * 384 + h * 16;
            bf16x8 qa = *(const bf16x8*)qp;
            bf16x8 qb = *(const bf16x8*)(qp + 8);
            #pragma unroll
            for (int e = 0; e < 8; ++e) {
                q[i][e] = b2f(qa[e]) * 0.25f;
                q[i][e + 8] = b2f(qb[e]) * 0.25f;
            }
        } else {
            #pragma unroll
            for (int e = 0; e < 16; ++e) q[i][e] = 0.f;
        }
    }
    float m[4], l[4], acc[4][16];
    #pragma unroll
    for (int i = 0; i < 4; ++i) {
        m[i] = -1e30f; l[i] = 0.f;
        #pragma unroll
        for (int e = 0; e < 16; ++e) acc[i][e] = 0.f;
    }
    int half = tid >> 7;             // 0: K, 1: V
    int idx = tid & 127;
    int sn = idx >> 1, se = (idx & 1) * 8;
    int nkt = (N + 63) >> 6;
    for (int kt = 0; kt < nkt; ++kt) {
        int ng = kt * 64 + sn;
        bf16x8 hv = bf16x8{0, 0, 0, 0, 0, 0, 0, 0};
        if (ng < N)
            hv = *(const bf16x8*)(base + (size_t)ng * 384 + 128 + half * 128 + h * 16 + se);
        __syncthreads();
        float* dst = half ? &Vs[sn][se] : &Ks[sn][se];
        #pragma unroll
        for (int e = 0; e < 8; ++e) dst[e] = b2f(hv[e]);
        __syncthreads();
        int kvalid = N - kt * 64;
        float sc[4][4];
        #pragma unroll
        for (int i = 0; i < 4; ++i)
            #pragma unroll
            for (int j = 0; j < 4; ++j) sc[i][j] = 0.f;
        #pragma unroll
        for (int e = 0; e < 16; ++e) {
            float kvv[4];
            #pragma unroll
            for (int j = 0; j < 4; ++j) kvv[j] = Ks[tx * 4 + j][e];
            #pragma unroll
            for (int i = 0; i < 4; ++i)
                #pragma unroll
                for (int j = 0; j < 4; ++j) sc[i][j] += q[i][e] * kvv[j];
        }
        #pragma unroll
        for (int j = 0; j < 4; ++j) {
            if (tx * 4 + j >= kvalid) {
                #pragma unroll
                for (int i = 0; i < 4; ++i) sc[i][j] = -1e30f;
            }
        }
        #pragma unroll
        for (int i = 0; i < 4; ++i) {
            float tmax = fmaxf(fmaxf(sc[i][0], sc[i][1]), fmaxf(sc[i][2], sc[i][3]));
            tmax = fmaxf(tmax, __shfl_xor(tmax, 1));
            tmax = fmaxf(tmax, __shfl_xor(tmax, 2));
            tmax = fmaxf(tmax, __shfl_xor(tmax, 4));
            tmax = fmaxf(tmax, __shfl_xor(tmax, 8));
            float nm = fmaxf(m[i], tmax);
            float f = __expf(m[i] - nm);
            m[i] = nm;
            l[i] *= f;
            #pragma unroll
            for (int e = 0; e < 16; ++e) acc[i][e] *= f;
            float p[4];
            float ls = 0.f;
            #pragma unroll
            for (int j = 0; j < 4; ++j) { p[j] = __expf(sc[i][j] - nm); ls += p[j]; }
            l[i] += ls;
            #pragma unroll
            for (int j = 0; j < 4; ++j)
                #pragma unroll
                for (int e = 0; e < 16; ++e) acc[i][e] += p[j] * Vs[tx * 4 + j][e];
        }
    }
    #pragma unroll
    for (int i = 0; i < 4; ++i) {
        #pragma unroll
        for (int s = 1; s < 16; s <<= 1) l[i] += __shfl_xor(l[i], s);
        #pragma unroll
        for (int e = 0; e < 16; ++e) {
            #pragma unroll
            for (int s = 1; s < 16; s <<= 1) acc[i][e] += __shfl_xor(acc[i][e], s);
        }
    }
    __syncthreads();
    float* ylds = &Ks[0][0];
    if (tx == 0) {
        #pragma unroll
        for (int i = 0; i < 4; ++i) {
            float inv = 1.0f / l[i];
            #pragma unroll
            for (int e = 0; e < 16; ++e) ylds[(ty * 4 + i) * 16 + e] = acc[i][e] * inv;
        }
    }
    __syncthreads();
    #pragma unroll
    for (int it = 0; it < 4; ++it) {
        int idx2 = tid + it * 256;
        int row = idx2 >> 4, e = idx2 & 15;
        int qi = qt * 64 + row;
        if (qi < N) out[((size_t)b * N + qi) * D_ + h * 16 + e] = f2b(ylds[row * 16 + e]);
    }
}

// ---------------------------------------------------------------------------
__global__ void dec_build_kernel(const float* __restrict__ dembed, const float* __restrict__ mask_token,
                                 const float* __restrict__ pos, const int* __restrict__ rank,
                                 float* __restrict__ outp) {
    int i = blockIdx.x, b = blockIdx.y;
    int d = threadIdx.x;
    int r = rank[b * G_ + i];
    float v = (r < KEEP_) ? dembed[((size_t)b * NENC_ + 1 + r) * D_ + d] : mask_token[d];
    outp[((size_t)b * G_ + i) * D_ + d] = v + pos[(size_t)i * D_ + d];
}

__global__ void cls_copy_kernel(const short* __restrict__ latent, float* __restrict__ outc) {
    int t = blockIdx.x * 128 + threadIdx.x;
    int b = t >> 7, d = t & 127;
    outc[t] = b2f(latent[(size_t)b * NENC_ * D_ + d]);
}

// ---------------------------------------------------------------------------
__global__ void pred_loss_kernel(const short* __restrict__ dln, const float* __restrict__ pw,
                                 const float* __restrict__ pb, const float* __restrict__ x,
                                 const int* __restrict__ rank,
                                 float* __restrict__ pred_out, float* __restrict__ bsums) {
    int tid = threadIdx.x;
    int wave = tid >> 6, lane = tid & 63;
    int row = blockIdx.x * 4 + wave;
    const short* rp = dln + (size_t)row * D_;
    float s = b2f(rp[lane]) * pw[lane] + b2f(rp[lane + 64]) * pw[lane + 64];
    #pragma unroll
    for (int o = 1; o < 64; o <<= 1) s += __shfl_xor(s, o);
    __shared__ float ps[4];
    if (lane == 0) {
        float pred = s + pb[0];
        pred_out[row] = pred;
        float diff = pred - x[row];
        float msk = (rank[row] >= KEEP_) ? 1.0f : 0.0f;
        ps[wave] = diff * diff * msk;
    }
    __syncthreads();
    if (tid == 0) bsums[blockIdx.x] = ps[0] + ps[1] + ps[2] + ps[3];
}

__global__ void loss_fin_kernel(const float* __restrict__ bs, float* __restrict__ out0) {
    int t = threadIdx.x;
    float s = 0.f;
    for (int i = t; i < 2048; i += 256) s += bs[i];
    #pragma unroll
    for (int o = 1; o < 64; o <<= 1) s += __shfl_xor(s, o);
    __shared__ float ps[4];
    if ((t & 63) == 0) ps[t >> 6] = s;
    __syncthreads();
    if (t == 0) out0[0] = (ps[0] + ps[1] + ps[2] + ps[3]) * (1.0f / 6144.0f);
}

// ---------------------------------------------------------------------------
extern "C" void kernel_launch(void* const* d_in, const int* in_sizes, int n_in,
                              void* d_out, int out_size, void* d_ws, size_t ws_size,
                              hipStream_t stream) {
    const float* x     = (const float*)d_in[0];
    const float* noise = (const float*)d_in[1];
    const float* pos   = (const float*)d_in[2];
    const float* cls   = (const float*)d_in[3];
    const float* eew   = (const float*)d_in[4];
    const float* eeb   = (const float*)d_in[5];
    const float* nw    = (const float*)d_in[6];
    const float* nb    = (const float*)d_in[7];
    const float* dew   = (const float*)d_in[8];
    const float* deb   = (const float*)d_in[9];
    const float* mtok  = (const float*)d_in[10];
    const float* dnw   = (const float*)d_in[11];
    const float* dnb   = (const float*)d_in[12];
    const float* pw    = (const float*)d_in[13];
    const float* pb    = (const float*)d_in[14];
    const float* eln1w = (const float*)d_in[15];
    const float* eln1b = (const float*)d_in[16];
    const float* eqkvw = (const float*)d_in[17];
    const float* eqkvb = (const float*)d_in[18];
    const float* eprjw = (const float*)d_in[19];
    const float* eprjb = (const float*)d_in[20];
    const float* eln2w = (const float*)d_in[21];
    const float* eln2b = (const float*)d_in[22];
    const float* ef1w  = (const float*)d_in[23];
    const float* ef1b  = (const float*)d_in[24];
    const float* ef2w  = (const float*)d_in[25];
    const float* ef2b  = (const float*)d_in[26];
    const float* dln1w = (const float*)d_in[27];
    const float* dln1b = (const float*)d_in[28];
    const float* dqkvw = (const float*)d_in[29];
    const float* dqkvb = (const float*)d_in[30];
    const float* dprjw = (const float*)d_in[31];
    const float* dprjb = (const float*)d_in[32];
    const float* dln2w = (const float*)d_in[33];
    const float* dln2b = (const float*)d_in[34];
    const float* df1w  = (const float*)d_in[35];
    const float* df1b  = (const float*)d_in[36];
    const float* df2w  = (const float*)d_in[37];
    const float* df2b  = (const float*)d_in[38];

    char* ws = (char*)d_ws;
    int*   rank    = (int*)(ws + 0);              // 32768
    int*   keep    = (int*)(ws + 32768);          // 8192
    float* bsums   = (float*)(ws + 40960);        // 8192
    float* enc_x   = (float*)(ws + 49152);        // 2052*128*4 = 1050624
    float* decx    = (float*)(ws + 1099776);      // 8192*128*4 = 4194304
    short* qkvb16  = (short*)(ws + 5294080);      // 8192*384*2 = 6291456
    short* attnb16 = (short*)(ws + 11585536);     // 8192*128*2 = 2097152
    short* lnb16   = (short*)(ws + 13682688);     // 2097152
    short* gelub16 = (short*)(ws + 15779840);     // 8192*512*2 = 8388608
    short* latb16  = (short*)(ws + 24168448);     // 2176*128*2 = 557056
    float* demb    = (float*)(ws + 24725504);     // 2052*128*4 = 1050624
    short* eqkvT   = (short*)(ws + 25776128);     // 6*384*128*2 = 589824
    short* eprjT   = (short*)(ws + 26365952);     // 6*128*128*2 = 196608
    short* ef1T    = (short*)(ws + 26562560);     // 6*512*128*2 = 786432
    short* ef2T    = (short*)(ws + 27348992);     // 6*128*512*2 = 786432
    short* dqkvT   = (short*)(ws + 28135424);     // 196608
    short* dprjT   = (short*)(ws + 28332032);     // 65536
    short* df1T    = (short*)(ws + 28397568);     // 262144
    short* df2T    = (short*)(ws + 28659712);     // 262144
    short* dembT   = (short*)(ws + 28921856);     // 32768  -> total ~28.95 MB

    float* outp = (float*)d_out;
    float* pred_out = outp + 1;
    float* mask_out = outp + 1 + B_ * G_;
    float* cls_out  = outp + 1 + 2 * B_ * G_;

    // ---- weight transposes (fp32 -> bf16 W^T) ----
    wtrans_kernel<<<dim3(384/32, 128/32, 6), 256, 0, stream>>>(eqkvw, eqkvT, 128, 384);
    wtrans_kernel<<<dim3(128/32, 128/32, 6), 256, 0, stream>>>(eprjw, eprjT, 128, 128);
    wtrans_kernel<<<dim3(512/32, 128/32, 6), 256, 0, stream>>>(ef1w,  ef1T,  128, 512);
    wtrans_kernel<<<dim3(128/32, 512/32, 6), 256, 0, stream>>>(ef2w,  ef2T,  512, 128);
    wtrans_kernel<<<dim3(384/32, 128/32, 2), 256, 0, stream>>>(dqkvw, dqkvT, 128, 384);
    wtrans_kernel<<<dim3(128/32, 128/32, 2), 256, 0, stream>>>(dprjw, dprjT, 128, 128);
    wtrans_kernel<<<dim3(512/32, 128/32, 2), 256, 0, stream>>>(df1w,  df1T,  128, 512);
    wtrans_kernel<<<dim3(128/32, 512/32, 2), 256, 0, stream>>>(df2w,  df2T,  512, 128);
    wtrans_kernel<<<dim3(128/32, 128/32, 1), 256, 0, stream>>>(dew,   dembT, 128, 128);

    // ---- masking / shuffle ----
    rank_kernel<<<dim3(G_ / 256, B_), 256, 0, stream>>>(noise, rank, keep, mask_out);
    embed_gather_kernel<<<dim3(NENC_, B_), 128, 0, stream>>>(x, pos, cls, eew, eeb, keep, enc_x);

    const int Menc = B_ * NENC_;                 // 2052
    const int gmE = (Menc + 127) / 128;          // 17
    for (int L = 0; L < 6; ++L) {
        ln_kernel<<<Menc, 128, 0, stream>>>(enc_x, lnb16, eln1w + L * D_, eln1b + L * D_);
        gemm_mfma_kernel<3><<<dim3(gmE, 3), 256, 0, stream>>>(lnb16, eqkvT + (size_t)L * 384 * 128,
                                                              eqkvb + L * 384, nullptr, qkvb16, Menc, 128, 384);
        attn_kernel<<<dim3((NENC_ + 63) / 64, NH_, B_), 256, 0, stream>>>(qkvb16, attnb16, NENC_);
        gemm_mfma_kernel<2><<<dim3(gmE, 1), 256, 0, stream>>>(attnb16, eprjT + (size_t)L * 128 * 128,
                                                              eprjb + L * D_, enc_x, enc_x, Menc, 128, 128);
        ln_kernel<<<Menc, 128, 0, stream>>>(enc_x, lnb16, eln2w + L * D_, eln2b + L * D_);
        gemm_mfma_kernel<1><<<dim3(gmE, 4), 256, 0, stream>>>(lnb16, ef1T + (size_t)L * 512 * 128,
                                                              ef1b + L * HID_, nullptr, gelub16, Menc, 128, 512);
        gemm_mfma_kernel<2><<<dim3(gmE, 1), 256, 0, stream>>>(gelub16, ef2T + (size_t)L * 128 * 512,
                                                              ef2b + L * D_, enc_x, enc_x, Menc, 512, 128);
    }
    ln_kernel<<<Menc, 128, 0, stream>>>(enc_x, latb16, nw, nb);
    cls_copy_kernel<<<4, 128, 0, stream>>>(latb16, cls_out);

    // ---- decoder embed + unshuffle ----
    gemm_mfma_kernel<0><<<dim3(gmE, 1), 256, 0, stream>>>(latb16, dembT, deb, nullptr, demb, Menc, 128, 128);
    dec_build_kernel<<<dim3(G_, B_), 128, 0, stream>>>(demb, mtok, pos, rank, decx);

    // ---- decoder ----
    const int Mdec = B_ * G_;                    // 8192
    const int gmD = Mdec / 128;                  // 64
    for (int L = 0; L < 2; ++L) {
        ln_kernel<<<Mdec, 128, 0, stream>>>(decx, lnb16, dln1w + L * D_, dln1b + L * D_);
        gemm_mfma_kernel<3><<<dim3(gmD, 3), 256, 0, stream>>>(lnb16, dqkvT + (size_t)L * 384 * 128,
                                                              dqkvb + L * 384, nullptr, qkvb16, Mdec, 128, 384);
        attn_kernel<<<dim3(G_ / 64, NH_, B_), 256, 0, stream>>>(qkvb16, attnb16, G_);
        gemm_mfma_kernel<2><<<dim3(gmD, 1), 256, 0, stream>>>(attnb16, dprjT + (size_t)L * 128 * 128,
                                                              dprjb + L * D_, decx, decx, Mdec, 128, 128);
        ln_kernel<<<Mdec, 128, 0, stream>>>(decx, lnb16, dln2w + L * D_, dln2b + L * D_);
        gemm_mfma_kernel<1><<<dim3(gmD, 4), 256, 0, stream>>>(lnb16, df1T + (size_t)L * 512 * 128,
                                                              df1b + L * HID_, nullptr, gelub16, Mdec, 128, 512);
        gemm_mfma_kernel<2><<<dim3(gmD, 1), 256, 0, stream>>>(gelub16, df2T + (size_t)L * 128 * 512,
                                                              df2b + L * D_, decx, decx, Mdec, 512, 128);
    }
    ln_kernel<<<Mdec, 128, 0, stream>>>(decx, lnb16, dnw, dnb);

    // ---- prediction + loss ----
    pred_loss_kernel<<<Mdec / 4, 256, 0, stream>>>(lnb16, pw, pb, x, rank, pred_out, bsums);
    loss_fin_kernel<<<1, 256, 0, stream>>>(bsums, outp);
}

// Round 4
// 858.855 us; speedup vs baseline: 1.6171x; 1.4606x over previous
//
#include <hip/hip_runtime.h>
#include <math.h>

#define D_ 128
#define NH_ 8
#define G_ 2048
#define B_ 4
#define KEEP_ 512
#define NENC_ 513
#define HID_ 512
#define EPS_ 1e-5f

typedef short bf16x8 __attribute__((ext_vector_type(8)));
typedef short s16x4 __attribute__((ext_vector_type(4)));
typedef float f32x4 __attribute__((ext_vector_type(4)));

static __device__ __forceinline__ float b2f(short s) {
    union { float f; unsigned u; } v;
    v.u = ((unsigned)(unsigned short)s) << 16;
    return v.f;
}
static __device__ __forceinline__ short f2b(float f) {
    union { float f; unsigned u; } v;
    v.f = f;
    unsigned r = v.u + 0x7fffu + ((v.u >> 16) & 1u);   // RNE
    return (short)(r >> 16);
}

// ---------------------------------------------------------------------------
// Stable rank of noise within each batch row.
// ---------------------------------------------------------------------------
__global__ void rank_kernel(const float* __restrict__ noise, int* __restrict__ rank,
                            int* __restrict__ keep_ids, float* __restrict__ mask_out) {
    int b = blockIdx.y;
    int i = blockIdx.x * 256 + threadIdx.x;
    __shared__ float sn[G_];
    const float* row = noise + (size_t)b * G_;
    for (int j = threadIdx.x; j < G_; j += 256) sn[j] = row[j];
    __syncthreads();
    float vi = sn[i];
    int r = 0;
    for (int j = 0; j < G_; ++j) {
        float vj = sn[j];
        r += (vj < vi) || (vj == vi && j < i);
    }
    rank[b * G_ + i] = r;
    mask_out[b * G_ + i] = (r >= KEEP_) ? 1.0f : 0.0f;
    if (r < KEEP_) keep_ids[b * KEEP_ + r] = i;
}

// ---------------------------------------------------------------------------
__global__ void embed_gather_kernel(const float* __restrict__ x, const float* __restrict__ pos,
                                    const float* __restrict__ cls, const float* __restrict__ ew,
                                    const float* __restrict__ eb, const int* __restrict__ keep_ids,
                                    float* __restrict__ h) {
    int n = blockIdx.x, b = blockIdx.y;
    int d = threadIdx.x;
    float v;
    if (n == 0) v = cls[d];
    else {
        int i = keep_ids[b * KEEP_ + (n - 1)];
        v = x[b * G_ + i] * ew[d] + eb[d] + pos[(size_t)i * D_ + d];
    }
    h[((size_t)b * NENC_ + n) * D_ + d] = v;
}

// ---------------------------------------------------------------------------
// Weight transpose + bf16 cast: src (L,K,N) f32 -> dst (L,N,K) bf16
// ---------------------------------------------------------------------------
__global__ void wtrans_kernel(const float* __restrict__ src, short* __restrict__ dst,
                              int K, int N) {
    int l = blockIdx.z;
    __shared__ float t[32][33];
    int n0 = blockIdx.x * 32, k0 = blockIdx.y * 32;
    const float* s = src + (size_t)l * K * N;
    short* d = dst + (size_t)l * N * K;
    int tx = threadIdx.x & 31, ty = threadIdx.x >> 5;   // 256 thr: ty 0..7
    #pragma unroll
    for (int i = 0; i < 32; i += 8)
        t[ty + i][tx] = s[(size_t)(k0 + ty + i) * N + n0 + tx];
    __syncthreads();
    #pragma unroll
    for (int i = 0; i < 32; i += 8)
        d[(size_t)(n0 + ty + i) * K + k0 + tx] = f2b(t[tx][ty + i]);
}

// ---------------------------------------------------------------------------
// LayerNorm, fp32 in -> bf16 out
// ---------------------------------------------------------------------------
__global__ void ln_kernel(const float* __restrict__ in, short* __restrict__ out,
                          const float* __restrict__ g, const float* __restrict__ bta) {
    int row = blockIdx.x;
    int t = threadIdx.x;
    float v = in[(size_t)row * D_ + t];
    float s = v;
    #pragma unroll
    for (int o = 1; o < 64; o <<= 1) s += __shfl_xor(s, o);
    __shared__ float ss[2];
    __shared__ float qq[2];
    if ((t & 63) == 0) ss[t >> 6] = s;
    __syncthreads();
    float mu = (ss[0] + ss[1]) * (1.0f / D_);
    float dv = v - mu;
    float q = dv * dv;
    #pragma unroll
    for (int o = 1; o < 64; o <<= 1) q += __shfl_xor(q, o);
    if ((t & 63) == 0) qq[t >> 6] = q;
    __syncthreads();
    float var = (qq[0] + qq[1]) * (1.0f / D_);
    out[(size_t)row * D_ + t] = f2b(dv * rsqrtf(var + EPS_) * g[t] + bta[t]);
}

// ---------------------------------------------------------------------------
// bf16 MFMA GEMM: C = A(MxK bf16) @ W(KxN) + bias.  Wt = W^T (N x K, bf16).
// MODE: 0 fp32 out, 1 gelu->bf16, 2 +R fp32 out, 3 bf16 out
// ---------------------------------------------------------------------------
template<int MODE>
__global__ __launch_bounds__(256) void gemm_mfma_kernel(
    const short* __restrict__ A, const short* __restrict__ Wt,
    const float* __restrict__ bias, const float* __restrict__ R,
    void* __restrict__ Cout, int M, int K, int N) {
    __shared__ short As[128 * 64];
    __shared__ short Bs[128 * 64];
    int tid = threadIdx.x;
    int lane = tid & 63, wid = tid >> 6;
    int wr = wid >> 1, wc = wid & 1;
    int bm = blockIdx.x * 128, bn = blockIdx.y * 128;
    int l15 = lane & 15, lhi = lane >> 4;
    f32x4 acc[4][4];
    #pragma unroll
    for (int m = 0; m < 4; ++m)
        #pragma unroll
        for (int n = 0; n < 4; ++n) acc[m][n] = f32x4{0.f, 0.f, 0.f, 0.f};

    const char* Ab = (const char*)A;
    const char* Bb = (const char*)Wt;
    char* AsB = (char*)As;
    char* BsB = (char*)Bs;
    int p = tid * 16;
    int r0 = p >> 7, cb0 = p & 127;

    for (int k0 = 0; k0 < K; k0 += 64) {
        __syncthreads();
        #pragma unroll
        for (int it = 0; it < 4; ++it) {
            int r = r0 + it * 32;
            int scb = cb0 ^ ((r & 7) << 4);
            __builtin_amdgcn_global_load_lds(
                (const __attribute__((address_space(1))) void*)(Ab + (((size_t)(bm + r) * K + k0) << 1) + scb),
                (__attribute__((address_space(3))) void*)(AsB + it * 4096 + (wid << 10)), 16, 0, 0);
            __builtin_amdgcn_global_load_lds(
                (const __attribute__((address_space(1))) void*)(Bb + (((size_t)(bn + r) * K + k0) << 1) + scb),
                (__attribute__((address_space(3))) void*)(BsB + it * 4096 + (wid << 10)), 16, 0, 0);
        }
        asm volatile("s_waitcnt vmcnt(0)" ::: "memory");
        __syncthreads();
        #pragma unroll
        for (int kk = 0; kk < 2; ++kk) {
            bf16x8 a[4], b[4];
            int cbb = kk * 64 + lhi * 16;
            #pragma unroll
            for (int m = 0; m < 4; ++m) {
                int row = wr * 64 + m * 16 + l15;
                a[m] = *(const bf16x8*)(AsB + row * 128 + (cbb ^ ((row & 7) << 4)));
                int rowb = wc * 64 + m * 16 + l15;
                b[m] = *(const bf16x8*)(BsB + rowb * 128 + (cbb ^ ((rowb & 7) << 4)));
            }
            #pragma unroll
            for (int m = 0; m < 4; ++m)
                #pragma unroll
                for (int n = 0; n < 4; ++n)
                    acc[m][n] = __builtin_amdgcn_mfma_f32_16x16x32_bf16(a[m], b[n], acc[m][n], 0, 0, 0);
        }
    }
    #pragma unroll
    for (int m = 0; m < 4; ++m) {
        int rbase = bm + wr * 64 + m * 16 + lhi * 4;
        #pragma unroll
        for (int n = 0; n < 4; ++n) {
            int col = bn + wc * 64 + n * 16 + l15;
            float bv = bias[col];
            #pragma unroll
            for (int j = 0; j < 4; ++j) {
                int rr = rbase + j;
                if (rr < M) {
                    float v = acc[m][n][j] + bv;
                    if (MODE == 1) {
                        v = 0.5f * v * (1.0f + erff(v * 0.70710678118654752f));
                        ((short*)Cout)[(size_t)rr * N + col] = f2b(v);
                    } else if (MODE == 2) {
                        ((float*)Cout)[(size_t)rr * N + col] = v + R[(size_t)rr * N + col];
                    } else if (MODE == 3) {
                        ((short*)Cout)[(size_t)rr * N + col] = f2b(v);
                    } else {
                        ((float*)Cout)[(size_t)rr * N + col] = v;
                    }
                }
            }
        }
    }
}

// ---------------------------------------------------------------------------
// MFMA flash attention. hd=16, H=8. qkv row: 384 bf16 [q|k|v], head h at h*16.
// Block: 4 waves, each owns a 16-row q-tile; 64 kv rows per iteration.
// Swapped QK^T (mfma(K,Q) -> S^T: lane holds scores for q=lane&15) with K rows
// staged permuted by gp(r)=32(r>>4>>1)+8((r&15)>>2)+4((r>>4)&1)+(r&3) so the
// S^T output registers are directly the PV B-fragment (no cross-lane moves).
// V^T fragments read as 16 scalar ds_read_u16 (unambiguous semantics).
// ---------------------------------------------------------------------------
__global__ __launch_bounds__(256) void attn_mfma_kernel(
    const short* __restrict__ qkv, short* __restrict__ out, int N) {
    int h = blockIdx.y, b = blockIdx.z;
    int tid = threadIdx.x;
    int lane = tid & 63, wid = tid >> 6;
    int l15 = lane & 15, lhi = lane >> 4;
    __shared__ __align__(16) short smem[2][2048];   // per buf: K 64x16 | V 64x16

    const short* base = qkv + (size_t)b * N * 384;

    // Q fragment (B-operand): lane holds Q[q=l15][hd=(lhi&1)*8..+8]; zero lhi>=2
    int q0w = blockIdx.x * 64 + wid * 16;
    int qi = q0w + l15;
    int qc = qi < N ? qi : N - 1;
    bf16x8 qf = *(const bf16x8*)(base + (size_t)qc * 384 + h * 16 + (lhi & 1) * 8);
    if (lhi >= 2) qf = bf16x8{0, 0, 0, 0, 0, 0, 0, 0};

    // staging: waves 0,1 -> K (permuted rows), waves 2,3 -> V (linear rows)
    bool isK = (wid < 2);
    int r64 = ((wid & 1) << 5) | (lane >> 1);
    int hb = lane & 1;
    int t_ = r64 >> 4, rr = r64 & 15;
    int gp = ((t_ >> 1) << 5) | ((rr >> 2) << 3) | ((t_ & 1) << 2) | (rr & 3);
    int grow = isK ? gp : r64;
    int soff = (isK ? 128 : 256) + h * 16 + hb * 8;
    int ldsWaveOff = (isK ? 0 : 2048) + ((wid & 1) << 10);   // bytes

    f32x4 acc = f32x4{0.f, 0.f, 0.f, 0.f};
    float mrun = -1e30f, lrun = 0.f;
    int nkt = (N + 63) >> 6;

#define STAGE(KT, BUFI) do {                                                        \
        int row_ = (KT) * 64 + grow;                                                \
        row_ = row_ < N ? row_ : N - 1;                                             \
        __builtin_amdgcn_global_load_lds(                                           \
            (const __attribute__((address_space(1))) void*)(base + (size_t)row_ * 384 + soff), \
            (__attribute__((address_space(3))) void*)((char*)&smem[BUFI][0] + ldsWaveOff), 16, 0, 0); \
    } while (0)

    STAGE(0, 0);
    for (int kt = 0; kt < nkt; ++kt) {
        int bf = kt & 1;
        if (kt + 1 < nkt) {
            STAGE(kt + 1, bf ^ 1);
            asm volatile("s_waitcnt vmcnt(1)" ::: "memory");
        } else {
            asm volatile("s_waitcnt vmcnt(0)" ::: "memory");
        }
        __builtin_amdgcn_s_barrier();
        asm volatile("" ::: "memory");

        const short* kb = smem[bf];
        const short* vb = kb + 1024;   // elements

        // K fragments + S^T mfmas (lhi>=2 lanes feed k>=16, zeroed by qf=0)
        f32x4 s4[4];
        #pragma unroll
        for (int t = 0; t < 4; ++t) {
            bf16x8 kf = *(const bf16x8*)(kb + (t * 16 + l15) * 16 + (lhi & 1) * 8);
            s4[t] = __builtin_amdgcn_mfma_f32_16x16x32_bf16(kf, qf, f32x4{0.f, 0.f, 0.f, 0.f}, 0, 0, 0);
        }

        // softmax over this lane's 16 kv (q = l15); reduce max across lhi groups
        int kv0 = kt * 64;
        bool tail = (kv0 + 64 > N);
        float pvv[4][4];
        float mx = -1e30f;
        #pragma unroll
        for (int t = 0; t < 4; ++t)
            #pragma unroll
            for (int r = 0; r < 4; ++r) {
                float v = s4[t][r] * 0.25f;
                if (tail) {
                    int kvg = ((t >> 1) << 5) | (lhi << 3) | ((t & 1) << 2) | r;
                    if (kv0 + kvg >= N) v = -1e30f;
                }
                pvv[t][r] = v;
                mx = fmaxf(mx, v);
            }
        mx = fmaxf(mx, __shfl_xor(mx, 16));
        mx = fmaxf(mx, __shfl_xor(mx, 32));
        float mnew = fmaxf(mrun, mx);
        float fr = __expf(mrun - mnew);
        mrun = mnew;
        lrun *= fr;
        acc[0] *= fr; acc[1] *= fr; acc[2] *= fr; acc[3] *= fr;
        float psum = 0.f;
        #pragma unroll
        for (int t = 0; t < 4; ++t)
            #pragma unroll
            for (int r = 0; r < 4; ++r) {
                float pp = __expf(pvv[t][r] - mnew);
                pvv[t][r] = pp;
                psum += pp;
            }
        lrun += psum;

        bf16x8 pa0, pa1;
        #pragma unroll
        for (int r = 0; r < 4; ++r) {
            pa0[r] = f2b(pvv[0][r]); pa0[4 + r] = f2b(pvv[1][r]);
            pa1[r] = f2b(pvv[2][r]); pa1[4 + r] = f2b(pvv[3][r]);
        }

        // V^T fragments: vf0[i] = V[lhi*8+i][l15], vf1[i] = V[32+lhi*8+i][l15]
        bf16x8 vf0, vf1;
        #pragma unroll
        for (int i2 = 0; i2 < 8; ++i2) {
            vf0[i2] = vb[(lhi * 8 + i2) * 16 + l15];
            vf1[i2] = vb[(32 + lhi * 8 + i2) * 16 + l15];
        }
        acc = __builtin_amdgcn_mfma_f32_16x16x32_bf16(vf0, pa0, acc, 0, 0, 0);
        acc = __builtin_amdgcn_mfma_f32_16x16x32_bf16(vf1, pa1, acc, 0, 0, 0);

        asm volatile("s_waitcnt lgkmcnt(0)" ::: "memory");
        __builtin_amdgcn_s_barrier();
        asm volatile("" ::: "memory");
    }
#undef STAGE

    lrun += __shfl_xor(lrun, 16);
    lrun += __shfl_xor(lrun, 32);
    float inv = 1.0f / lrun;
    s16x4 o;
    #pragma unroll
    for (int r = 0; r < 4; ++r) o[r] = f2b(acc[r] * inv);
    if (qi < N)
        *(s16x4*)(out + ((size_t)b * N + qi) * D_ + h * 16 + lhi * 4) = o;
}

// ---------------------------------------------------------------------------
__global__ void dec_build_kernel(const float* __restrict__ dembed, const float* __restrict__ mask_token,
                                 const float* __restrict__ pos, const int* __restrict__ rank,
                                 float* __restrict__ outp) {
    int i = blockIdx.x, b = blockIdx.y;
    int d = threadIdx.x;
    int r = rank[b * G_ + i];
    float v = (r < KEEP_) ? dembed[((size_t)b * NENC_ + 1 + r) * D_ + d] : mask_token[d];
    outp[((size_t)b * G_ + i) * D_ + d] = v + pos[(size_t)i * D_ + d];
}

__global__ void cls_copy_kernel(const short* __restrict__ latent, float* __restrict__ outc) {
    int t = blockIdx.x * 128 + threadIdx.x;
    int b = t >> 7, d = t & 127;
    outc[t] = b2f(latent[(size_t)b * NENC_ * D_ + d]);
}

// ---------------------------------------------------------------------------
__global__ void pred_loss_kernel(const short* __restrict__ dln, const float* __restrict__ pw,
                                 const float* __restrict__ pb, const float* __restrict__ x,
                                 const int* __restrict__ rank,
                                 float* __restrict__ pred_out, float* __restrict__ bsums) {
    int tid = threadIdx.x;
    int wave = tid >> 6, lane = tid & 63;
    int row = blockIdx.x * 4 + wave;
    const short* rp = dln + (size_t)row * D_;
    float s = b2f(rp[lane]) * pw[lane] + b2f(rp[lane + 64]) * pw[lane + 64];
    #pragma unroll
    for (int o = 1; o < 64; o <<= 1) s += __shfl_xor(s, o);
    __shared__ float ps[4];
    if (lane == 0) {
        float pred = s + pb[0];
        pred_out[row] = pred;
        float diff = pred - x[row];
        float msk = (rank[row] >= KEEP_) ? 1.0f : 0.0f;
        ps[wave] = diff * diff * msk;
    }
    __syncthreads();
    if (tid == 0) bsums[blockIdx.x] = ps[0] + ps[1] + ps[2] + ps[3];
}

__global__ void loss_fin_kernel(const float* __restrict__ bs, float* __restrict__ out0) {
    int t = threadIdx.x;
    float s = 0.f;
    for (int i = t; i < 2048; i += 256) s += bs[i];
    #pragma unroll
    for (int o = 1; o < 64; o <<= 1) s += __shfl_xor(s, o);
    __shared__ float ps[4];
    if ((t & 63) == 0) ps[t >> 6] = s;
    __syncthreads();
    if (t == 0) out0[0] = (ps[0] + ps[1] + ps[2] + ps[3]) * (1.0f / 6144.0f);
}

// ---------------------------------------------------------------------------
extern "C" void kernel_launch(void* const* d_in, const int* in_sizes, int n_in,
                              void* d_out, int out_size, void* d_ws, size_t ws_size,
                              hipStream_t stream) {
    const float* x     = (const float*)d_in[0];
    const float* noise = (const float*)d_in[1];
    const float* pos   = (const float*)d_in[2];
    const float* cls   = (const float*)d_in[3];
    const float* eew   = (const float*)d_in[4];
    const float* eeb   = (const float*)d_in[5];
    const float* nw    = (const float*)d_in[6];
    const float* nb    = (const float*)d_in[7];
    const float* dew   = (const float*)d_in[8];
    const float* deb   = (const float*)d_in[9];
    const float* mtok  = (const float*)d_in[10];
    const float* dnw   = (const float*)d_in[11];
    const float* dnb   = (const float*)d_in[12];
    const float* pw    = (const float*)d_in[13];
    const float* pb    = (const float*)d_in[14];
    const float* eln1w = (const float*)d_in[15];
    const float* eln1b = (const float*)d_in[16];
    const float* eqkvw = (const float*)d_in[17];
    const float* eqkvb = (const float*)d_in[18];
    const float* eprjw = (const float*)d_in[19];
    const float* eprjb = (const float*)d_in[20];
    const float* eln2w = (const float*)d_in[21];
    const float* eln2b = (const float*)d_in[22];
    const float* ef1w  = (const float*)d_in[23];
    const float* ef1b  = (const float*)d_in[24];
    const float* ef2w  = (const float*)d_in[25];
    const float* ef2b  = (const float*)d_in[26];
    const float* dln1w = (const float*)d_in[27];
    const float* dln1b = (const float*)d_in[28];
    const float* dqkvw = (const float*)d_in[29];
    const float* dqkvb = (const float*)d_in[30];
    const float* dprjw = (const float*)d_in[31];
    const float* dprjb = (const float*)d_in[32];
    const float* dln2w = (const float*)d_in[33];
    const float* dln2b = (const float*)d_in[34];
    const float* df1w  = (const float*)d_in[35];
    const float* df1b  = (const float*)d_in[36];
    const float* df2w  = (const float*)d_in[37];
    const float* df2b  = (const float*)d_in[38];

    char* ws = (char*)d_ws;
    int*   rank    = (int*)(ws + 0);              // 32768
    int*   keep    = (int*)(ws + 32768);          // 8192
    float* bsums   = (float*)(ws + 40960);        // 8192
    float* enc_x   = (float*)(ws + 49152);        // 1050624
    float* decx    = (float*)(ws + 1099776);      // 4194304
    short* qkvb16  = (short*)(ws + 5294080);      // 6291456
    short* attnb16 = (short*)(ws + 11585536);     // 2097152
    short* lnb16   = (short*)(ws + 13682688);     // 2097152
    short* gelub16 = (short*)(ws + 15779840);     // 8388608
    short* latb16  = (short*)(ws + 24168448);     // 557056
    float* demb    = (float*)(ws + 24725504);     // 1050624
    short* eqkvT   = (short*)(ws + 25776128);     // 589824
    short* eprjT   = (short*)(ws + 26365952);     // 196608
    short* ef1T    = (short*)(ws + 26562560);     // 786432
    short* ef2T    = (short*)(ws + 27348992);     // 786432
    short* dqkvT   = (short*)(ws + 28135424);     // 196608
    short* dprjT   = (short*)(ws + 28332032);     // 65536
    short* df1T    = (short*)(ws + 28397568);     // 262144
    short* df2T    = (short*)(ws + 28659712);     // 262144
    short* dembT   = (short*)(ws + 28921856);     // 32768

    float* outp = (float*)d_out;
    float* pred_out = outp + 1;
    float* mask_out = outp + 1 + B_ * G_;
    float* cls_out  = outp + 1 + 2 * B_ * G_;

    // ---- weight transposes (fp32 -> bf16 W^T) ----
    wtrans_kernel<<<dim3(384/32, 128/32, 6), 256, 0, stream>>>(eqkvw, eqkvT, 128, 384);
    wtrans_kernel<<<dim3(128/32, 128/32, 6), 256, 0, stream>>>(eprjw, eprjT, 128, 128);
    wtrans_kernel<<<dim3(512/32, 128/32, 6), 256, 0, stream>>>(ef1w,  ef1T,  128, 512);
    wtrans_kernel<<<dim3(128/32, 512/32, 6), 256, 0, stream>>>(ef2w,  ef2T,  512, 128);
    wtrans_kernel<<<dim3(384/32, 128/32, 2), 256, 0, stream>>>(dqkvw, dqkvT, 128, 384);
    wtrans_kernel<<<dim3(128/32, 128/32, 2), 256, 0, stream>>>(dprjw, dprjT, 128, 128);
    wtrans_kernel<<<dim3(512/32, 128/32, 2), 256, 0, stream>>>(df1w,  df1T,  128, 512);
    wtrans_kernel<<<dim3(128/32, 512/32, 2), 256, 0, stream>>>(df2w,  df2T,  512, 128);
    wtrans_kernel<<<dim3(128/32, 128/32, 1), 256, 0, stream>>>(dew,   dembT, 128, 128);

    // ---- masking / shuffle ----
    rank_kernel<<<dim3(G_ / 256, B_), 256, 0, stream>>>(noise, rank, keep, mask_out);
    embed_gather_kernel<<<dim3(NENC_, B_), 128, 0, stream>>>(x, pos, cls, eew, eeb, keep, enc_x);

    const int Menc = B_ * NENC_;                 // 2052
    const int gmE = (Menc + 127) / 128;          // 17
    for (int L = 0; L < 6; ++L) {
        ln_kernel<<<Menc, 128, 0, stream>>>(enc_x, lnb16, eln1w + L * D_, eln1b + L * D_);
        gemm_mfma_kernel<3><<<dim3(gmE, 3), 256, 0, stream>>>(lnb16, eqkvT + (size_t)L * 384 * 128,
                                                              eqkvb + L * 384, nullptr, qkvb16, Menc, 128, 384);
        attn_mfma_kernel<<<dim3((NENC_ + 63) / 64, NH_, B_), 256, 0, stream>>>(qkvb16, attnb16, NENC_);
        gemm_mfma_kernel<2><<<dim3(gmE, 1), 256, 0, stream>>>(attnb16, eprjT + (size_t)L * 128 * 128,
                                                              eprjb + L * D_, enc_x, enc_x, Menc, 128, 128);
        ln_kernel<<<Menc, 128, 0, stream>>>(enc_x, lnb16, eln2w + L * D_, eln2b + L * D_);
        gemm_mfma_kernel<1><<<dim3(gmE, 4), 256, 0, stream>>>(lnb16, ef1T + (size_t)L * 512 * 128,
                                                              ef1b + L * HID_, nullptr, gelub16, Menc, 128, 512);
        gemm_mfma_kernel<2><<<dim3(gmE, 1), 256, 0, stream>>>(gelub16, ef2T + (size_t)L * 128 * 512,
                                                              ef2b + L * D_, enc_x, enc_x, Menc, 512, 128);
    }
    ln_kernel<<<Menc, 128, 0, stream>>>(enc_x, latb16, nw, nb);
    cls_copy_kernel<<<4, 128, 0, stream>>>(latb16, cls_out);

    // ---- decoder embed + unshuffle ----
    gemm_mfma_kernel<0><<<dim3(gmE, 1), 256, 0, stream>>>(latb16, dembT, deb, nullptr, demb, Menc, 128, 128);
    dec_build_kernel<<<dim3(G_, B_), 128, 0, stream>>>(demb, mtok, pos, rank, decx);

    // ---- decoder ----
    const int Mdec = B_ * G_;                    // 8192
    const int gmD = Mdec / 128;                  // 64
    for (int L = 0; L < 2; ++L) {
        ln_kernel<<<Mdec, 128, 0, stream>>>(decx, lnb16, dln1w + L * D_, dln1b + L * D_);
        gemm_mfma_kernel<3><<<dim3(gmD, 3), 256, 0, stream>>>(lnb16, dqkvT + (size_t)L * 384 * 128,
                                                              dqkvb + L * 384, nullptr, qkvb16, Mdec, 128, 384);
        attn_mfma_kernel<<<dim3(G_ / 64, NH_, B_), 256, 0, stream>>>(qkvb16, attnb16, G_);
        gemm_mfma_kernel<2><<<dim3(gmD, 1), 256, 0, stream>>>(attnb16, dprjT + (size_t)L * 128 * 128,
                                                              dprjb + L * D_, decx, decx, Mdec, 128, 128);
        ln_kernel<<<Mdec, 128, 0, stream>>>(decx, lnb16, dln2w + L * D_, dln2b + L * D_);
        gemm_mfma_kernel<1><<<dim3(gmD, 4), 256, 0, stream>>>(lnb16, df1T + (size_t)L * 512 * 128,
                                                              df1b + L * HID_, nullptr, gelub16, Mdec, 128, 512);
        gemm_mfma_kernel<2><<<dim3(gmD, 1), 256, 0, stream>>>(gelub16, df2T + (size_t)L * 128 * 512,
                                                              df2b + L * D_, decx, decx, Mdec, 512, 128);
    }
    ln_kernel<<<Mdec, 128, 0, stream>>>(decx, lnb16, dnw, dnb);

    // ---- prediction + loss ----
    pred_loss_kernel<<<Mdec / 4, 256, 0, stream>>>(lnb16, pw, pb, x, rank, pred_out, bsums);
    loss_fin_kernel<<<1, 256, 0, stream>>>(bsums, outp);
}

// Round 5
// 755.798 us; speedup vs baseline: 1.8376x; 1.1364x over previous
//
#include <hip/hip_runtime.h>
#include <math.h>

#define D_ 128
#define NH_ 8
#define G_ 2048
#define B_ 4
#define KEEP_ 512
#define NENC_ 513
#define HID_ 512
#define EPS_ 1e-5f

typedef short bf16x8 __attribute__((ext_vector_type(8)));
typedef short s16x4 __attribute__((ext_vector_type(4)));
typedef float f32x4 __attribute__((ext_vector_type(4)));

static __device__ __forceinline__ float b2f(short s) {
    union { float f; unsigned u; } v;
    v.u = ((unsigned)(unsigned short)s) << 16;
    return v.f;
}
static __device__ __forceinline__ short f2b(float f) {
    union { float f; unsigned u; } v;
    v.f = f;
    unsigned r = v.u + 0x7fffu + ((v.u >> 16) & 1u);   // RNE
    return (short)(r >> 16);
}
static __device__ __forceinline__ unsigned cvtpk(float lo, float hi) {
    unsigned r;
    asm("v_cvt_pk_bf16_f32 %0, %1, %2" : "=v"(r) : "v"(lo), "v"(hi));
    return r;
}

// ---------------------------------------------------------------------------
// Stable rank of noise within each batch row.
// ---------------------------------------------------------------------------
__global__ void rank_kernel(const float* __restrict__ noise, int* __restrict__ rank,
                            int* __restrict__ keep_ids, float* __restrict__ mask_out) {
    int b = blockIdx.y;
    int i = blockIdx.x * 256 + threadIdx.x;
    __shared__ float sn[G_];
    const float* row = noise + (size_t)b * G_;
    for (int j = threadIdx.x; j < G_; j += 256) sn[j] = row[j];
    __syncthreads();
    float vi = sn[i];
    int r = 0;
    for (int j = 0; j < G_; ++j) {
        float vj = sn[j];
        r += (vj < vi) || (vj == vi && j < i);
    }
    rank[b * G_ + i] = r;
    mask_out[b * G_ + i] = (r >= KEEP_) ? 1.0f : 0.0f;
    if (r < KEEP_) keep_ids[b * KEEP_ + r] = i;
}

// ---------------------------------------------------------------------------
// All 9 weight transposes in one launch. z selects the matrix.
// src (K,N) f32 -> dst (N,K) bf16
// ---------------------------------------------------------------------------
__global__ void prep_kernel(
    const float* __restrict__ eqkvw, const float* __restrict__ eprjw,
    const float* __restrict__ ef1w,  const float* __restrict__ ef2w,
    const float* __restrict__ dqkvw, const float* __restrict__ dprjw,
    const float* __restrict__ df1w,  const float* __restrict__ df2w,
    const float* __restrict__ dew,
    short* eqkvT, short* eprjT, short* ef1T, short* ef2T,
    short* dqkvT, short* dprjT, short* df1T, short* df2T, short* dembT) {
    int z = blockIdx.z;
    const float* s; short* d; int K, N;
    if (z < 6)       { int l = z;      s = eqkvw + (size_t)l * 128 * 384; d = eqkvT + (size_t)l * 384 * 128; K = 128; N = 384; }
    else if (z < 12) { int l = z - 6;  s = eprjw + (size_t)l * 128 * 128; d = eprjT + (size_t)l * 128 * 128; K = 128; N = 128; }
    else if (z < 18) { int l = z - 12; s = ef1w  + (size_t)l * 128 * 512; d = ef1T  + (size_t)l * 512 * 128; K = 128; N = 512; }
    else if (z < 24) { int l = z - 18; s = ef2w  + (size_t)l * 512 * 128; d = ef2T  + (size_t)l * 128 * 512; K = 512; N = 128; }
    else if (z < 26) { int l = z - 24; s = dqkvw + (size_t)l * 128 * 384; d = dqkvT + (size_t)l * 384 * 128; K = 128; N = 384; }
    else if (z < 28) { int l = z - 26; s = dprjw + (size_t)l * 128 * 128; d = dprjT + (size_t)l * 128 * 128; K = 128; N = 128; }
    else if (z < 30) { int l = z - 28; s = df1w  + (size_t)l * 128 * 512; d = df1T  + (size_t)l * 512 * 128; K = 128; N = 512; }
    else if (z < 32) { int l = z - 30; s = df2w  + (size_t)l * 512 * 128; d = df2T  + (size_t)l * 128 * 512; K = 512; N = 128; }
    else             { s = dew; d = dembT; K = 128; N = 128; }
    int n0 = blockIdx.x * 32, k0 = blockIdx.y * 32;
    if (n0 >= N || k0 >= K) return;
    __shared__ float t[32][33];
    int tx = threadIdx.x & 31, ty = threadIdx.x >> 5;
    #pragma unroll
    for (int i = 0; i < 32; i += 8)
        t[ty + i][tx] = s[(size_t)(k0 + ty + i) * N + n0 + tx];
    __syncthreads();
    #pragma unroll
    for (int i = 0; i < 32; i += 8)
        d[(size_t)(n0 + ty + i) * K + k0 + tx] = f2b(t[tx][ty + i]);
}

// ---------------------------------------------------------------------------
// LN helper body for 128-thread one-row blocks
// ---------------------------------------------------------------------------
static __device__ __forceinline__ float row_ln_128(float v, int t, const float* g,
                                                   const float* bta, float* ss, float* qq) {
    float s = v;
    #pragma unroll
    for (int o = 1; o < 64; o <<= 1) s += __shfl_xor(s, o);
    if ((t & 63) == 0) ss[t >> 6] = s;
    __syncthreads();
    float mu = (ss[0] + ss[1]) * (1.0f / D_);
    float dv = v - mu;
    float q = dv * dv;
    #pragma unroll
    for (int o = 1; o < 64; o <<= 1) q += __shfl_xor(q, o);
    if ((t & 63) == 0) qq[t >> 6] = q;
    __syncthreads();
    float var = (qq[0] + qq[1]) * (1.0f / D_);
    return dv * rsqrtf(var + EPS_) * g[t] + bta[t];
}

// ---------------------------------------------------------------------------
// embed + gather + first-layer LN fused
// ---------------------------------------------------------------------------
__global__ void embed_ln_kernel(const float* __restrict__ x, const float* __restrict__ pos,
                                const float* __restrict__ cls, const float* __restrict__ ew,
                                const float* __restrict__ eb, const int* __restrict__ keep_ids,
                                const float* __restrict__ lnw, const float* __restrict__ lnb,
                                float* __restrict__ resid, short* __restrict__ lout) {
    int n = blockIdx.x, b = blockIdx.y;
    int t = threadIdx.x;
    float v;
    if (n == 0) v = cls[t];
    else {
        int i = keep_ids[b * KEEP_ + (n - 1)];
        v = x[b * G_ + i] * ew[t] + eb[t] + pos[(size_t)i * D_ + t];
    }
    size_t row = (size_t)b * NENC_ + n;
    resid[row * D_ + t] = v;
    __shared__ float ss[2], qq[2];
    lout[row * D_ + t] = f2b(row_ln_128(v, t, lnw, lnb, ss, qq));
}

// ---------------------------------------------------------------------------
// decoder build (unshuffle + mask token + pos) + first dec LN fused
// ---------------------------------------------------------------------------
__global__ void decbuild_ln_kernel(const float* __restrict__ dembed, const float* __restrict__ mask_token,
                                   const float* __restrict__ pos, const int* __restrict__ rank,
                                   const float* __restrict__ lnw, const float* __restrict__ lnb,
                                   float* __restrict__ resid, short* __restrict__ lout) {
    int i = blockIdx.x, b = blockIdx.y;
    int t = threadIdx.x;
    int r = rank[b * G_ + i];
    float v = (r < KEEP_) ? dembed[((size_t)b * NENC_ + 1 + r) * D_ + t] : mask_token[t];
    v += pos[(size_t)i * D_ + t];
    size_t row = (size_t)b * G_ + i;
    resid[row * D_ + t] = v;
    __shared__ float ss[2], qq[2];
    lout[row * D_ + t] = f2b(row_ln_128(v, t, lnw, lnb, ss, qq));
}

// ---------------------------------------------------------------------------
// bf16 MFMA GEMM: C = A(MxK bf16) @ W(KxN) + bias.  Wt = W^T (N x K, bf16).
// MODE 0: fp32 out            MODE 1: gelu -> bf16 out    MODE 3: bf16 out
// MODE 4: +R -> resid fp32 out AND LN -> bf16 Lout  (requires N==128, grid.y==1)
// MODE 5: +R -> LN -> bf16 Lout (no resid write)
// MODE 6: +R -> LN -> pred head dot + masked loss partials (no resid write)
// ---------------------------------------------------------------------------
template<int MODE>
__global__ __launch_bounds__(256) void gemm_mfma_kernel(
    const short* __restrict__ A, const short* __restrict__ Wt,
    const float* __restrict__ bias, const float* R,
    void* Cout, int M, int K, int N,
    const float* __restrict__ lnw, const float* __restrict__ lnb,
    short* __restrict__ Lout,
    const float* __restrict__ pwv, const float* __restrict__ pbv,
    const float* __restrict__ xin, const int* __restrict__ rankp,
    float* __restrict__ predp, float* __restrict__ bsumsp) {
    __shared__ short As[128 * 64];
    __shared__ short Bs[128 * 64];
    int tid = threadIdx.x;
    int lane = tid & 63, wid = tid >> 6;
    int wr = wid >> 1, wc = wid & 1;
    int bm = blockIdx.x * 128, bn = blockIdx.y * 128;
    int l15 = lane & 15, lhi = lane >> 4;
    f32x4 acc[4][4];
    #pragma unroll
    for (int m = 0; m < 4; ++m)
        #pragma unroll
        for (int n = 0; n < 4; ++n) acc[m][n] = f32x4{0.f, 0.f, 0.f, 0.f};

    const char* Ab = (const char*)A;
    const char* Bb = (const char*)Wt;
    char* AsB = (char*)As;
    char* BsB = (char*)Bs;
    int p = tid * 16;
    int r0 = p >> 7, cb0 = p & 127;

    for (int k0 = 0; k0 < K; k0 += 64) {
        __syncthreads();
        #pragma unroll
        for (int it = 0; it < 4; ++it) {
            int r = r0 + it * 32;
            int scb = cb0 ^ ((r & 7) << 4);
            __builtin_amdgcn_global_load_lds(
                (const __attribute__((address_space(1))) void*)(Ab + (((size_t)(bm + r) * K + k0) << 1) + scb),
                (__attribute__((address_space(3))) void*)(AsB + it * 4096 + (wid << 10)), 16, 0, 0);
            __builtin_amdgcn_global_load_lds(
                (const __attribute__((address_space(1))) void*)(Bb + (((size_t)(bn + r) * K + k0) << 1) + scb),
                (__attribute__((address_space(3))) void*)(BsB + it * 4096 + (wid << 10)), 16, 0, 0);
        }
        asm volatile("s_waitcnt vmcnt(0)" ::: "memory");
        __syncthreads();
        #pragma unroll
        for (int kk = 0; kk < 2; ++kk) {
            bf16x8 a[4], b[4];
            int cbb = kk * 64 + lhi * 16;
            #pragma unroll
            for (int m = 0; m < 4; ++m) {
                int row = wr * 64 + m * 16 + l15;
                a[m] = *(const bf16x8*)(AsB + row * 128 + (cbb ^ ((row & 7) << 4)));
                int rowb = wc * 64 + m * 16 + l15;
                b[m] = *(const bf16x8*)(BsB + rowb * 128 + (cbb ^ ((rowb & 7) << 4)));
            }
            #pragma unroll
            for (int m = 0; m < 4; ++m)
                #pragma unroll
                for (int n = 0; n < 4; ++n)
                    acc[m][n] = __builtin_amdgcn_mfma_f32_16x16x32_bf16(a[m], b[n], acc[m][n], 0, 0, 0);
        }
    }

    if (MODE == 0 || MODE == 1 || MODE == 3) {
        #pragma unroll
        for (int m = 0; m < 4; ++m) {
            int rbase = bm + wr * 64 + m * 16 + lhi * 4;
            #pragma unroll
            for (int n = 0; n < 4; ++n) {
                int col = bn + wc * 64 + n * 16 + l15;
                float bv = bias[col];
                #pragma unroll
                for (int j = 0; j < 4; ++j) {
                    int rr = rbase + j;
                    if (rr < M) {
                        float v = acc[m][n][j] + bv;
                        if (MODE == 1) {
                            v = 0.5f * v * (1.0f + erff(v * 0.70710678118654752f));
                            ((short*)Cout)[(size_t)rr * N + col] = f2b(v);
                        } else if (MODE == 3) {
                            ((short*)Cout)[(size_t)rr * N + col] = f2b(v);
                        } else {
                            ((float*)Cout)[(size_t)rr * N + col] = v;
                        }
                    }
                }
            }
        }
        return;
    }

    // ---- fused residual + LN epilogue (N==128, grid.y==1) ----
    #pragma unroll
    for (int m = 0; m < 4; ++m) {
        #pragma unroll
        for (int n = 0; n < 4; ++n) {
            int col = wc * 64 + n * 16 + l15;
            float bv = bias[col];
            #pragma unroll
            for (int j = 0; j < 4; ++j) {
                int rr = bm + wr * 64 + m * 16 + lhi * 4 + j;
                int rc = rr < M ? rr : M - 1;
                acc[m][n][j] += bv + R[(size_t)rc * 128 + col];
            }
        }
    }
    if (MODE == 4) {
        #pragma unroll
        for (int m = 0; m < 4; ++m)
            #pragma unroll
            for (int n = 0; n < 4; ++n) {
                int col = wc * 64 + n * 16 + l15;
                #pragma unroll
                for (int j = 0; j < 4; ++j) {
                    int rr = bm + wr * 64 + m * 16 + lhi * 4 + j;
                    if (rr < M) ((float*)Cout)[(size_t)rr * 128 + col] = acc[m][n][j];
                }
            }
    }
    __syncthreads();
    float* sst = (float*)As;                // [128][4]: (wc, {sum,sq})
    #pragma unroll
    for (int m = 0; m < 4; ++m)
        #pragma unroll
        for (int j = 0; j < 4; ++j) {
            float ps = 0.f, pq = 0.f;
            #pragma unroll
            for (int n = 0; n < 4; ++n) { float t0 = acc[m][n][j]; ps += t0; pq += t0 * t0; }
            #pragma unroll
            for (int o = 1; o < 16; o <<= 1) { ps += __shfl_xor(ps, o); pq += __shfl_xor(pq, o); }
            if (l15 == 0) {
                int row = wr * 64 + m * 16 + lhi * 4 + j;
                sst[row * 4 + wc * 2 + 0] = ps;
                sst[row * 4 + wc * 2 + 1] = pq;
            }
        }
    __syncthreads();
    float pwl[4];
    if (MODE == 6) {
        #pragma unroll
        for (int n = 0; n < 4; ++n) pwl[n] = pwv[wc * 64 + n * 16 + l15];
    }
    float pp[4][4];
    #pragma unroll
    for (int m = 0; m < 4; ++m)
        #pragma unroll
        for (int j = 0; j < 4; ++j) {
            int row = wr * 64 + m * 16 + lhi * 4 + j;
            int rr = bm + row;
            float s0 = sst[row * 4 + 0] + sst[row * 4 + 2];
            float q0 = sst[row * 4 + 1] + sst[row * 4 + 3];
            float mu = s0 * (1.0f / 128.0f);
            float var = q0 * (1.0f / 128.0f) - mu * mu;
            float rs = rsqrtf(var + EPS_);
            float pacc = 0.f;
            #pragma unroll
            for (int n = 0; n < 4; ++n) {
                int col = wc * 64 + n * 16 + l15;
                float lnv = (acc[m][n][j] - mu) * rs * lnw[col] + lnb[col];
                if (MODE != 6) {
                    if (rr < M) Lout[(size_t)rr * 128 + col] = f2b(lnv);
                } else {
                    pacc += lnv * pwl[n];
                }
            }
            pp[m][j] = pacc;
        }
    if (MODE == 6) {
        float* sp = (float*)As + 512;       // [128][2]
        #pragma unroll
        for (int m = 0; m < 4; ++m)
            #pragma unroll
            for (int j = 0; j < 4; ++j) {
                float v2 = pp[m][j];
                #pragma unroll
                for (int o = 1; o < 16; o <<= 1) v2 += __shfl_xor(v2, o);
                if (l15 == 0) {
                    int row = wr * 64 + m * 16 + lhi * 4 + j;
                    sp[row * 2 + wc] = v2;
                }
            }
        __syncthreads();
        float* rl = (float*)As + 768;       // [128]
        if (tid < 128) {
            int gr = bm + tid;
            float pred = sp[tid * 2] + sp[tid * 2 + 1] + pbv[0];
            predp[gr] = pred;
            float dd = pred - xin[gr];
            float msk = (rankp[gr] >= KEEP_) ? 1.0f : 0.0f;
            rl[tid] = dd * dd * msk;
        }
        __syncthreads();
        if (tid < 64) {
            float s2 = rl[tid] + rl[tid + 64];
            #pragma unroll
            for (int o = 1; o < 64; o <<= 1) s2 += __shfl_xor(s2, o);
            if (tid == 0) bsumsp[blockIdx.x] = s2;
        }
    }
}

// ---------------------------------------------------------------------------
// MFMA flash attention (as round 4, verified) + cvt_pk packing.
// ---------------------------------------------------------------------------
__global__ __launch_bounds__(256) void attn_mfma_kernel(
    const short* __restrict__ qkv, short* __restrict__ out, int N) {
    int h = blockIdx.y, b = blockIdx.z;
    int tid = threadIdx.x;
    int lane = tid & 63, wid = tid >> 6;
    int l15 = lane & 15, lhi = lane >> 4;
    __shared__ __align__(16) short smem[2][2048];   // per buf: K 64x16 | V 64x16

    const short* base = qkv + (size_t)b * N * 384;

    int q0w = blockIdx.x * 64 + wid * 16;
    int qi = q0w + l15;
    int qc = qi < N ? qi : N - 1;
    bf16x8 qf = *(const bf16x8*)(base + (size_t)qc * 384 + h * 16 + (lhi & 1) * 8);
    if (lhi >= 2) qf = bf16x8{0, 0, 0, 0, 0, 0, 0, 0};

    bool isK = (wid < 2);
    int r64 = ((wid & 1) << 5) | (lane >> 1);
    int hb = lane & 1;
    int t_ = r64 >> 4, rr = r64 & 15;
    int gp = ((t_ >> 1) << 5) | ((rr >> 2) << 3) | ((t_ & 1) << 2) | (rr & 3);
    int grow = isK ? gp : r64;
    int soff = (isK ? 128 : 256) + h * 16 + hb * 8;
    int ldsWaveOff = (isK ? 0 : 2048) + ((wid & 1) << 10);   // bytes

    f32x4 acc = f32x4{0.f, 0.f, 0.f, 0.f};
    float mrun = -1e30f, lrun = 0.f;
    int nkt = (N + 63) >> 6;

#define STAGE(KT, BUFI) do {                                                        \
        int row_ = (KT) * 64 + grow;                                                \
        row_ = row_ < N ? row_ : N - 1;                                             \
        __builtin_amdgcn_global_load_lds(                                           \
            (const __attribute__((address_space(1))) void*)(base + (size_t)row_ * 384 + soff), \
            (__attribute__((address_space(3))) void*)((char*)&smem[BUFI][0] + ldsWaveOff), 16, 0, 0); \
    } while (0)

    STAGE(0, 0);
    for (int kt = 0; kt < nkt; ++kt) {
        int bf = kt & 1;
        if (kt + 1 < nkt) {
            STAGE(kt + 1, bf ^ 1);
            asm volatile("s_waitcnt vmcnt(1)" ::: "memory");
        } else {
            asm volatile("s_waitcnt vmcnt(0)" ::: "memory");
        }
        __builtin_amdgcn_s_barrier();
        asm volatile("" ::: "memory");

        const short* kb = smem[bf];
        const short* vb = kb + 1024;   // elements

        f32x4 s4[4];
        #pragma unroll
        for (int t = 0; t < 4; ++t) {
            bf16x8 kf = *(const bf16x8*)(kb + (t * 16 + l15) * 16 + (lhi & 1) * 8);
            s4[t] = __builtin_amdgcn_mfma_f32_16x16x32_bf16(kf, qf, f32x4{0.f, 0.f, 0.f, 0.f}, 0, 0, 0);
        }

        int kv0 = kt * 64;
        bool tail = (kv0 + 64 > N);
        float pvv[4][4];
        float mx = -1e30f;
        #pragma unroll
        for (int t = 0; t < 4; ++t)
            #pragma unroll
            for (int r = 0; r < 4; ++r) {
                float v = s4[t][r] * 0.25f;
                if (tail) {
                    int kvg = ((t >> 1) << 5) | (lhi << 3) | ((t & 1) << 2) | r;
                    if (kv0 + kvg >= N) v = -1e30f;
                }
                pvv[t][r] = v;
                mx = fmaxf(mx, v);
            }
        mx = fmaxf(mx, __shfl_xor(mx, 16));
        mx = fmaxf(mx, __shfl_xor(mx, 32));
        float mnew = fmaxf(mrun, mx);
        float fr = __expf(mrun - mnew);
        mrun = mnew;
        lrun *= fr;
        acc[0] *= fr; acc[1] *= fr; acc[2] *= fr; acc[3] *= fr;
        float psum = 0.f;
        #pragma unroll
        for (int t = 0; t < 4; ++t)
            #pragma unroll
            for (int r = 0; r < 4; ++r) {
                float pp = __expf(pvv[t][r] - mnew);
                pvv[t][r] = pp;
                psum += pp;
            }
        lrun += psum;

        union { bf16x8 v8; unsigned u[4]; } pa0u, pa1u;
        pa0u.u[0] = cvtpk(pvv[0][0], pvv[0][1]);
        pa0u.u[1] = cvtpk(pvv[0][2], pvv[0][3]);
        pa0u.u[2] = cvtpk(pvv[1][0], pvv[1][1]);
        pa0u.u[3] = cvtpk(pvv[1][2], pvv[1][3]);
        pa1u.u[0] = cvtpk(pvv[2][0], pvv[2][1]);
        pa1u.u[1] = cvtpk(pvv[2][2], pvv[2][3]);
        pa1u.u[2] = cvtpk(pvv[3][0], pvv[3][1]);
        pa1u.u[3] = cvtpk(pvv[3][2], pvv[3][3]);

        bf16x8 vf0, vf1;
        #pragma unroll
        for (int i2 = 0; i2 < 8; ++i2) {
            vf0[i2] = vb[(lhi * 8 + i2) * 16 + l15];
            vf1[i2] = vb[(32 + lhi * 8 + i2) * 16 + l15];
        }
        acc = __builtin_amdgcn_mfma_f32_16x16x32_bf16(vf0, pa0u.v8, acc, 0, 0, 0);
        acc = __builtin_amdgcn_mfma_f32_16x16x32_bf16(vf1, pa1u.v8, acc, 0, 0, 0);

        asm volatile("s_waitcnt lgkmcnt(0)" ::: "memory");
        __builtin_amdgcn_s_barrier();
        asm volatile("" ::: "memory");
    }
#undef STAGE

    lrun += __shfl_xor(lrun, 16);
    lrun += __shfl_xor(lrun, 32);
    float inv = 1.0f / lrun;
    s16x4 o;
    #pragma unroll
    for (int r = 0; r < 4; ++r) o[r] = f2b(acc[r] * inv);
    if (qi < N)
        *(s16x4*)(out + ((size_t)b * N + qi) * D_ + h * 16 + lhi * 4) = o;
}

// ---------------------------------------------------------------------------
__global__ void cls_copy_kernel(const short* __restrict__ latent, float* __restrict__ outc) {
    int t = blockIdx.x * 128 + threadIdx.x;
    int b = t >> 7, d = t & 127;
    outc[t] = b2f(latent[(size_t)b * NENC_ * D_ + d]);
}

__global__ void loss_fin_kernel(const float* __restrict__ bs, float* __restrict__ out0) {
    int t = threadIdx.x;   // 64
    float s = bs[t];
    #pragma unroll
    for (int o = 1; o < 64; o <<= 1) s += __shfl_xor(s, o);
    if (t == 0) out0[0] = s * (1.0f / 6144.0f);
}

// ---------------------------------------------------------------------------
extern "C" void kernel_launch(void* const* d_in, const int* in_sizes, int n_in,
                              void* d_out, int out_size, void* d_ws, size_t ws_size,
                              hipStream_t stream) {
    const float* x     = (const float*)d_in[0];
    const float* noise = (const float*)d_in[1];
    const float* pos   = (const float*)d_in[2];
    const float* cls   = (const float*)d_in[3];
    const float* eew   = (const float*)d_in[4];
    const float* eeb   = (const float*)d_in[5];
    const float* nw    = (const float*)d_in[6];
    const float* nb    = (const float*)d_in[7];
    const float* dew   = (const float*)d_in[8];
    const float* deb   = (const float*)d_in[9];
    const float* mtok  = (const float*)d_in[10];
    const float* dnw   = (const float*)d_in[11];
    const float* dnb   = (const float*)d_in[12];
    const float* pw    = (const float*)d_in[13];
    const float* pb    = (const float*)d_in[14];
    const float* eln1w = (const float*)d_in[15];
    const float* eln1b = (const float*)d_in[16];
    const float* eqkvw = (const float*)d_in[17];
    const float* eqkvb = (const float*)d_in[18];
    const float* eprjw = (const float*)d_in[19];
    const float* eprjb = (const float*)d_in[20];
    const float* eln2w = (const float*)d_in[21];
    const float* eln2b = (const float*)d_in[22];
    const float* ef1w  = (const float*)d_in[23];
    const float* ef1b  = (const float*)d_in[24];
    const float* ef2w  = (const float*)d_in[25];
    const float* ef2b  = (const float*)d_in[26];
    const float* dln1w = (const float*)d_in[27];
    const float* dln1b = (const float*)d_in[28];
    const float* dqkvw = (const float*)d_in[29];
    const float* dqkvb = (const float*)d_in[30];
    const float* dprjw = (const float*)d_in[31];
    const float* dprjb = (const float*)d_in[32];
    const float* dln2w = (const float*)d_in[33];
    const float* dln2b = (const float*)d_in[34];
    const float* df1w  = (const float*)d_in[35];
    const float* df1b  = (const float*)d_in[36];
    const float* df2w  = (const float*)d_in[37];
    const float* df2b  = (const float*)d_in[38];

    char* ws = (char*)d_ws;
    int*   rank    = (int*)(ws + 0);              // 32768
    int*   keep    = (int*)(ws + 32768);          // 8192
    float* bsums   = (float*)(ws + 40960);        // 8192
    float* enc_x   = (float*)(ws + 49152);        // 1050624
    float* decx    = (float*)(ws + 1099776);      // 4194304
    short* qkvb16  = (short*)(ws + 5294080);      // 6291456
    short* attnb16 = (short*)(ws + 11585536);     // 2097152
    short* lnb16   = (short*)(ws + 13682688);     // 2097152
    short* gelub16 = (short*)(ws + 15779840);     // 8388608
    short* latb16  = (short*)(ws + 24168448);     // 557056
    float* demb    = (float*)(ws + 24725504);     // 1050624
    short* eqkvT   = (short*)(ws + 25776128);     // 589824
    short* eprjT   = (short*)(ws + 26365952);     // 196608
    short* ef1T    = (short*)(ws + 26562560);     // 786432
    short* ef2T    = (short*)(ws + 27348992);     // 786432
    short* dqkvT   = (short*)(ws + 28135424);     // 196608
    short* dprjT   = (short*)(ws + 28332032);     // 65536
    short* df1T    = (short*)(ws + 28397568);     // 262144
    short* df2T    = (short*)(ws + 28659712);     // 262144
    short* dembT   = (short*)(ws + 28921856);     // 32768

    float* outp = (float*)d_out;
    float* pred_out = outp + 1;
    float* mask_out = outp + 1 + B_ * G_;
    float* cls_out  = outp + 1 + 2 * B_ * G_;

#define NIL nullptr, nullptr, nullptr, nullptr, nullptr, nullptr, nullptr, nullptr, nullptr

    prep_kernel<<<dim3(16, 16, 33), 256, 0, stream>>>(
        eqkvw, eprjw, ef1w, ef2w, dqkvw, dprjw, df1w, df2w, dew,
        eqkvT, eprjT, ef1T, ef2T, dqkvT, dprjT, df1T, df2T, dembT);

    rank_kernel<<<dim3(G_ / 256, B_), 256, 0, stream>>>(noise, rank, keep, mask_out);
    embed_ln_kernel<<<dim3(NENC_, B_), 128, 0, stream>>>(x, pos, cls, eew, eeb, keep,
                                                         eln1w, eln1b, enc_x, lnb16);

    const int Menc = B_ * NENC_;                 // 2052
    const int gmE = (Menc + 127) / 128;          // 17
    for (int L = 0; L < 6; ++L) {
        gemm_mfma_kernel<3><<<dim3(gmE, 3), 256, 0, stream>>>(lnb16, eqkvT + (size_t)L * 384 * 128,
            eqkvb + L * 384, nullptr, qkvb16, Menc, 128, 384, NIL);
        attn_mfma_kernel<<<dim3((NENC_ + 63) / 64, NH_, B_), 256, 0, stream>>>(qkvb16, attnb16, NENC_);
        gemm_mfma_kernel<4><<<dim3(gmE, 1), 256, 0, stream>>>(attnb16, eprjT + (size_t)L * 128 * 128,
            eprjb + L * D_, enc_x, enc_x, Menc, 128, 128,
            eln2w + L * D_, eln2b + L * D_, lnb16, nullptr, nullptr, nullptr, nullptr, nullptr, nullptr);
        gemm_mfma_kernel<1><<<dim3(gmE, 4), 256, 0, stream>>>(lnb16, ef1T + (size_t)L * 512 * 128,
            ef1b + L * HID_, nullptr, gelub16, Menc, 128, 512, NIL);
        if (L < 5) {
            gemm_mfma_kernel<4><<<dim3(gmE, 1), 256, 0, stream>>>(gelub16, ef2T + (size_t)L * 128 * 512,
                ef2b + L * D_, enc_x, enc_x, Menc, 512, 128,
                eln1w + (L + 1) * D_, eln1b + (L + 1) * D_, lnb16, nullptr, nullptr, nullptr, nullptr, nullptr, nullptr);
        } else {
            gemm_mfma_kernel<5><<<dim3(gmE, 1), 256, 0, stream>>>(gelub16, ef2T + (size_t)L * 128 * 512,
                ef2b + L * D_, enc_x, enc_x, Menc, 512, 128,
                nw, nb, latb16, nullptr, nullptr, nullptr, nullptr, nullptr, nullptr);
        }
    }
    cls_copy_kernel<<<4, 128, 0, stream>>>(latb16, cls_out);

    // ---- decoder embed + unshuffle + first dec LN ----
    gemm_mfma_kernel<0><<<dim3(gmE, 1), 256, 0, stream>>>(latb16, dembT, deb, nullptr, demb,
                                                          Menc, 128, 128, NIL);
    decbuild_ln_kernel<<<dim3(G_, B_), 128, 0, stream>>>(demb, mtok, pos, rank,
                                                         dln1w, dln1b, decx, lnb16);

    const int Mdec = B_ * G_;                    // 8192
    const int gmD = Mdec / 128;                  // 64
    for (int L = 0; L < 2; ++L) {
        gemm_mfma_kernel<3><<<dim3(gmD, 3), 256, 0, stream>>>(lnb16, dqkvT + (size_t)L * 384 * 128,
            dqkvb + L * 384, nullptr, qkvb16, Mdec, 128, 384, NIL);
        attn_mfma_kernel<<<dim3(G_ / 64, NH_, B_), 256, 0, stream>>>(qkvb16, attnb16, G_);
        gemm_mfma_kernel<4><<<dim3(gmD, 1), 256, 0, stream>>>(attnb16, dprjT + (size_t)L * 128 * 128,
            dprjb + L * D_, decx, decx, Mdec, 128, 128,
            dln2w + L * D_, dln2b + L * D_, lnb16, nullptr, nullptr, nullptr, nullptr, nullptr, nullptr);
        gemm_mfma_kernel<1><<<dim3(gmD, 4), 256, 0, stream>>>(lnb16, df1T + (size_t)L * 512 * 128,
            df1b + L * HID_, nullptr, gelub16, Mdec, 128, 512, NIL);
        if (L == 0) {
            gemm_mfma_kernel<4><<<dim3(gmD, 1), 256, 0, stream>>>(gelub16, df2T + (size_t)L * 128 * 512,
                df2b + L * D_, decx, decx, Mdec, 512, 128,
                dln1w + D_, dln1b + D_, lnb16, nullptr, nullptr, nullptr, nullptr, nullptr, nullptr);
        } else {
            gemm_mfma_kernel<6><<<dim3(gmD, 1), 256, 0, stream>>>(gelub16, df2T + (size_t)L * 128 * 512,
                df2b + L * D_, decx, decx, Mdec, 512, 128,
                dnw, dnb, nullptr, pw, pb, x, rank, pred_out, bsums);
        }
    }

    loss_fin_kernel<<<1, 64, 0, stream>>>(bsums, outp);
#undef NIL
}

// Round 6
// 743.140 us; speedup vs baseline: 1.8689x; 1.0170x over previous
//
#include <hip/hip_runtime.h>
#include <math.h>

#define D_ 128
#define NH_ 8
#define G_ 2048
#define B_ 4
#define KEEP_ 512
#define NENC_ 513
#define HID_ 512
#define EPS_ 1e-5f

typedef short bf16x8 __attribute__((ext_vector_type(8)));
typedef short s16x4 __attribute__((ext_vector_type(4)));
typedef float f32x4 __attribute__((ext_vector_type(4)));

static __device__ __forceinline__ float b2f(short s) {
    union { float f; unsigned u; } v;
    v.u = ((unsigned)(unsigned short)s) << 16;
    return v.f;
}
static __device__ __forceinline__ short f2b(float f) {
    union { float f; unsigned u; } v;
    v.f = f;
    unsigned r = v.u + 0x7fffu + ((v.u >> 16) & 1u);   // RNE
    return (short)(r >> 16);
}
static __device__ __forceinline__ unsigned cvtpk(float lo, float hi) {
    unsigned r;
    asm("v_cvt_pk_bf16_f32 %0, %1, %2" : "=v"(r) : "v"(lo), "v"(hi));
    return r;
}

// ---------------------------------------------------------------------------
// Stable rank of noise within each batch row.
// ---------------------------------------------------------------------------
__global__ void rank_kernel(const float* __restrict__ noise, int* __restrict__ rank,
                            int* __restrict__ keep_ids, float* __restrict__ mask_out) {
    int b = blockIdx.y;
    int i = blockIdx.x * 256 + threadIdx.x;
    __shared__ float sn[G_];
    const float* row = noise + (size_t)b * G_;
    for (int j = threadIdx.x; j < G_; j += 256) sn[j] = row[j];
    __syncthreads();
    float vi = sn[i];
    int r = 0;
    for (int j = 0; j < G_; ++j) {
        float vj = sn[j];
        r += (vj < vi) || (vj == vi && j < i);
    }
    rank[b * G_ + i] = r;
    mask_out[b * G_ + i] = (r >= KEEP_) ? 1.0f : 0.0f;
    if (r < KEEP_) keep_ids[b * KEEP_ + r] = i;
}

// ---------------------------------------------------------------------------
// All 9 weight transposes in one launch. z selects the matrix.
// ---------------------------------------------------------------------------
__global__ void prep_kernel(
    const float* __restrict__ eqkvw, const float* __restrict__ eprjw,
    const float* __restrict__ ef1w,  const float* __restrict__ ef2w,
    const float* __restrict__ dqkvw, const float* __restrict__ dprjw,
    const float* __restrict__ df1w,  const float* __restrict__ df2w,
    const float* __restrict__ dew,
    short* eqkvT, short* eprjT, short* ef1T, short* ef2T,
    short* dqkvT, short* dprjT, short* df1T, short* df2T, short* dembT) {
    int z = blockIdx.z;
    const float* s; short* d; int K, N;
    if (z < 6)       { int l = z;      s = eqkvw + (size_t)l * 128 * 384; d = eqkvT + (size_t)l * 384 * 128; K = 128; N = 384; }
    else if (z < 12) { int l = z - 6;  s = eprjw + (size_t)l * 128 * 128; d = eprjT + (size_t)l * 128 * 128; K = 128; N = 128; }
    else if (z < 18) { int l = z - 12; s = ef1w  + (size_t)l * 128 * 512; d = ef1T  + (size_t)l * 512 * 128; K = 128; N = 512; }
    else if (z < 24) { int l = z - 18; s = ef2w  + (size_t)l * 512 * 128; d = ef2T  + (size_t)l * 128 * 512; K = 512; N = 128; }
    else if (z < 26) { int l = z - 24; s = dqkvw + (size_t)l * 128 * 384; d = dqkvT + (size_t)l * 384 * 128; K = 128; N = 384; }
    else if (z < 28) { int l = z - 26; s = dprjw + (size_t)l * 128 * 128; d = dprjT + (size_t)l * 128 * 128; K = 128; N = 128; }
    else if (z < 30) { int l = z - 28; s = df1w  + (size_t)l * 128 * 512; d = df1T  + (size_t)l * 512 * 128; K = 128; N = 512; }
    else if (z < 32) { int l = z - 30; s = df2w  + (size_t)l * 512 * 128; d = df2T  + (size_t)l * 128 * 512; K = 512; N = 128; }
    else             { s = dew; d = dembT; K = 128; N = 128; }
    int n0 = blockIdx.x * 32, k0 = blockIdx.y * 32;
    if (n0 >= N || k0 >= K) return;
    __shared__ float t[32][33];
    int tx = threadIdx.x & 31, ty = threadIdx.x >> 5;
    #pragma unroll
    for (int i = 0; i < 32; i += 8)
        t[ty + i][tx] = s[(size_t)(k0 + ty + i) * N + n0 + tx];
    __syncthreads();
    #pragma unroll
    for (int i = 0; i < 32; i += 8)
        d[(size_t)(n0 + ty + i) * K + k0 + tx] = f2b(t[tx][ty + i]);
}

// ---------------------------------------------------------------------------
static __device__ __forceinline__ float row_ln_128(float v, int t, const float* g,
                                                   const float* bta, float* ss, float* qq) {
    float s = v;
    #pragma unroll
    for (int o = 1; o < 64; o <<= 1) s += __shfl_xor(s, o);
    if ((t & 63) == 0) ss[t >> 6] = s;
    __syncthreads();
    float mu = (ss[0] + ss[1]) * (1.0f / D_);
    float dv = v - mu;
    float q = dv * dv;
    #pragma unroll
    for (int o = 1; o < 64; o <<= 1) q += __shfl_xor(q, o);
    if ((t & 63) == 0) qq[t >> 6] = q;
    __syncthreads();
    float var = (qq[0] + qq[1]) * (1.0f / D_);
    return dv * rsqrtf(var + EPS_) * g[t] + bta[t];
}

// ---------------------------------------------------------------------------
__global__ void embed_ln_kernel(const float* __restrict__ x, const float* __restrict__ pos,
                                const float* __restrict__ cls, const float* __restrict__ ew,
                                const float* __restrict__ eb, const int* __restrict__ keep_ids,
                                const float* __restrict__ lnw, const float* __restrict__ lnb,
                                float* __restrict__ resid, short* __restrict__ lout) {
    int n = blockIdx.x, b = blockIdx.y;
    int t = threadIdx.x;
    float v;
    if (n == 0) v = cls[t];
    else {
        int i = keep_ids[b * KEEP_ + (n - 1)];
        v = x[b * G_ + i] * ew[t] + eb[t] + pos[(size_t)i * D_ + t];
    }
    size_t row = (size_t)b * NENC_ + n;
    resid[row * D_ + t] = v;
    __shared__ float ss[2], qq[2];
    lout[row * D_ + t] = f2b(row_ln_128(v, t, lnw, lnb, ss, qq));
}

// ---------------------------------------------------------------------------
__global__ void decbuild_ln_kernel(const float* __restrict__ dembed, const float* __restrict__ mask_token,
                                   const float* __restrict__ pos, const int* __restrict__ rank,
                                   const float* __restrict__ lnw, const float* __restrict__ lnb,
                                   float* __restrict__ resid, short* __restrict__ lout) {
    int i = blockIdx.x, b = blockIdx.y;
    int t = threadIdx.x;
    int r = rank[b * G_ + i];
    float v = (r < KEEP_) ? dembed[((size_t)b * NENC_ + 1 + r) * D_ + t] : mask_token[t];
    v += pos[(size_t)i * D_ + t];
    size_t row = (size_t)b * G_ + i;
    resid[row * D_ + t] = v;
    __shared__ float ss[2], qq[2];
    lout[row * D_ + t] = f2b(row_ln_128(v, t, lnw, lnb, ss, qq));
}

// ---------------------------------------------------------------------------
// bf16 MFMA GEMM.  MODE 0: fp32 out   MODE 1: gelu->bf16   MODE 3: bf16 out
//   (MODE 3 scales cols 0..127 (blockIdx.y==0 => Q of qkv) by 0.25)
// MODE 4: +R -> resid fp32 AND LN -> bf16 Lout   MODE 5: +R -> LN -> bf16 Lout
// MODE 6: +R -> LN -> pred head dot + masked loss partials
// ---------------------------------------------------------------------------
template<int MODE>
__global__ __launch_bounds__(256) void gemm_mfma_kernel(
    const short* __restrict__ A, const short* __restrict__ Wt,
    const float* __restrict__ bias, const float* R,
    void* Cout, int M, int K, int N,
    const float* __restrict__ lnw, const float* __restrict__ lnb,
    short* __restrict__ Lout,
    const float* __restrict__ pwv, const float* __restrict__ pbv,
    const float* __restrict__ xin, const int* __restrict__ rankp,
    float* __restrict__ predp, float* __restrict__ bsumsp) {
    __shared__ short As[128 * 64];
    __shared__ short Bs[128 * 64];
    int tid = threadIdx.x;
    int lane = tid & 63, wid = tid >> 6;
    int wr = wid >> 1, wc = wid & 1;
    int bm = blockIdx.x * 128, bn = blockIdx.y * 128;
    int l15 = lane & 15, lhi = lane >> 4;
    f32x4 acc[4][4];
    #pragma unroll
    for (int m = 0; m < 4; ++m)
        #pragma unroll
        for (int n = 0; n < 4; ++n) acc[m][n] = f32x4{0.f, 0.f, 0.f, 0.f};

    const char* Ab = (const char*)A;
    const char* Bb = (const char*)Wt;
    char* AsB = (char*)As;
    char* BsB = (char*)Bs;
    int p = tid * 16;
    int r0 = p >> 7, cb0 = p & 127;

    for (int k0 = 0; k0 < K; k0 += 64) {
        __syncthreads();
        #pragma unroll
        for (int it = 0; it < 4; ++it) {
            int r = r0 + it * 32;
            int scb = cb0 ^ ((r & 7) << 4);
            __builtin_amdgcn_global_load_lds(
                (const __attribute__((address_space(1))) void*)(Ab + (((size_t)(bm + r) * K + k0) << 1) + scb),
                (__attribute__((address_space(3))) void*)(AsB + it * 4096 + (wid << 10)), 16, 0, 0);
            __builtin_amdgcn_global_load_lds(
                (const __attribute__((address_space(1))) void*)(Bb + (((size_t)(bn + r) * K + k0) << 1) + scb),
                (__attribute__((address_space(3))) void*)(BsB + it * 4096 + (wid << 10)), 16, 0, 0);
        }
        asm volatile("s_waitcnt vmcnt(0)" ::: "memory");
        __syncthreads();
        #pragma unroll
        for (int kk = 0; kk < 2; ++kk) {
            bf16x8 a[4], b[4];
            int cbb = kk * 64 + lhi * 16;
            #pragma unroll
            for (int m = 0; m < 4; ++m) {
                int row = wr * 64 + m * 16 + l15;
                a[m] = *(const bf16x8*)(AsB + row * 128 + (cbb ^ ((row & 7) << 4)));
                int rowb = wc * 64 + m * 16 + l15;
                b[m] = *(const bf16x8*)(BsB + rowb * 128 + (cbb ^ ((rowb & 7) << 4)));
            }
            #pragma unroll
            for (int m = 0; m < 4; ++m)
                #pragma unroll
                for (int n = 0; n < 4; ++n)
                    acc[m][n] = __builtin_amdgcn_mfma_f32_16x16x32_bf16(a[m], b[n], acc[m][n], 0, 0, 0);
        }
    }

    if (MODE == 0 || MODE == 1 || MODE == 3) {
        float qsc = (MODE == 3 && blockIdx.y == 0) ? 0.25f : 1.0f;
        #pragma unroll
        for (int m = 0; m < 4; ++m) {
            int rbase = bm + wr * 64 + m * 16 + lhi * 4;
            #pragma unroll
            for (int n = 0; n < 4; ++n) {
                int col = bn + wc * 64 + n * 16 + l15;
                float bv = bias[col];
                #pragma unroll
                for (int j = 0; j < 4; ++j) {
                    int rr = rbase + j;
                    if (rr < M) {
                        float v = acc[m][n][j] + bv;
                        if (MODE == 1) {
                            v = 0.5f * v * (1.0f + erff(v * 0.70710678118654752f));
                            ((short*)Cout)[(size_t)rr * N + col] = f2b(v);
                        } else if (MODE == 3) {
                            ((short*)Cout)[(size_t)rr * N + col] = f2b(v * qsc);
                        } else {
                            ((float*)Cout)[(size_t)rr * N + col] = v;
                        }
                    }
                }
            }
        }
        return;
    }

    // ---- fused residual + LN epilogue (N==128, grid.y==1) ----
    #pragma unroll
    for (int m = 0; m < 4; ++m) {
        #pragma unroll
        for (int n = 0; n < 4; ++n) {
            int col = wc * 64 + n * 16 + l15;
            float bv = bias[col];
            #pragma unroll
            for (int j = 0; j < 4; ++j) {
                int rr = bm + wr * 64 + m * 16 + lhi * 4 + j;
                int rc = rr < M ? rr : M - 1;
                acc[m][n][j] += bv + R[(size_t)rc * 128 + col];
            }
        }
    }
    if (MODE == 4) {
        #pragma unroll
        for (int m = 0; m < 4; ++m)
            #pragma unroll
            for (int n = 0; n < 4; ++n) {
                int col = wc * 64 + n * 16 + l15;
                #pragma unroll
                for (int j = 0; j < 4; ++j) {
                    int rr = bm + wr * 64 + m * 16 + lhi * 4 + j;
                    if (rr < M) ((float*)Cout)[(size_t)rr * 128 + col] = acc[m][n][j];
                }
            }
    }
    __syncthreads();
    float* sst = (float*)As;
    #pragma unroll
    for (int m = 0; m < 4; ++m)
        #pragma unroll
        for (int j = 0; j < 4; ++j) {
            float ps = 0.f, pq = 0.f;
            #pragma unroll
            for (int n = 0; n < 4; ++n) { float t0 = acc[m][n][j]; ps += t0; pq += t0 * t0; }
            #pragma unroll
            for (int o = 1; o < 16; o <<= 1) { ps += __shfl_xor(ps, o); pq += __shfl_xor(pq, o); }
            if (l15 == 0) {
                int row = wr * 64 + m * 16 + lhi * 4 + j;
                sst[row * 4 + wc * 2 + 0] = ps;
                sst[row * 4 + wc * 2 + 1] = pq;
            }
        }
    __syncthreads();
    float pwl[4];
    if (MODE == 6) {
        #pragma unroll
        for (int n = 0; n < 4; ++n) pwl[n] = pwv[wc * 64 + n * 16 + l15];
    }
    float pp[4][4];
    #pragma unroll
    for (int m = 0; m < 4; ++m)
        #pragma unroll
        for (int j = 0; j < 4; ++j) {
            int row = wr * 64 + m * 16 + lhi * 4 + j;
            int rr = bm + row;
            float s0 = sst[row * 4 + 0] + sst[row * 4 + 2];
            float q0 = sst[row * 4 + 1] + sst[row * 4 + 3];
            float mu = s0 * (1.0f / 128.0f);
            float var = q0 * (1.0f / 128.0f) - mu * mu;
            float rs = rsqrtf(var + EPS_);
            float pacc = 0.f;
            #pragma unroll
            for (int n = 0; n < 4; ++n) {
                int col = wc * 64 + n * 16 + l15;
                float lnv = (acc[m][n][j] - mu) * rs * lnw[col] + lnb[col];
                if (MODE != 6) {
                    if (rr < M) Lout[(size_t)rr * 128 + col] = f2b(lnv);
                } else {
                    pacc += lnv * pwl[n];
                }
            }
            pp[m][j] = pacc;
        }
    if (MODE == 6) {
        float* sp = (float*)As + 512;
        #pragma unroll
        for (int m = 0; m < 4; ++m)
            #pragma unroll
            for (int j = 0; j < 4; ++j) {
                float v2 = pp[m][j];
                #pragma unroll
                for (int o = 1; o < 16; o <<= 1) v2 += __shfl_xor(v2, o);
                if (l15 == 0) {
                    int row = wr * 64 + m * 16 + lhi * 4 + j;
                    sp[row * 2 + wc] = v2;
                }
            }
        __syncthreads();
        float* rl = (float*)As + 768;
        if (tid < 128) {
            int gr = bm + tid;
            float pred = sp[tid * 2] + sp[tid * 2 + 1] + pbv[0];
            predp[gr] = pred;
            float dd = pred - xin[gr];
            float msk = (rankp[gr] >= KEEP_) ? 1.0f : 0.0f;
            rl[tid] = dd * dd * msk;
        }
        __syncthreads();
        if (tid < 64) {
            float s2 = rl[tid] + rl[tid + 64];
            #pragma unroll
            for (int o = 1; o < 64; o <<= 1) s2 += __shfl_xor(s2, o);
            if (tid == 0) bsumsp[blockIdx.x] = s2;
        }
    }
}

// ---------------------------------------------------------------------------
// MFMA flash attention (round-4-verified core). Q pre-scaled by 0.25 in qkv.
// SPLIT=0: full kv range, bf16 out.
// SPLIT=1: grid.x = 2*nqt; half=bx&1 handles kv half; writes fp32 partials
//   accp[half][B*N][128] and mlp[half][B*N][H][2].
// ---------------------------------------------------------------------------
template<int SPLIT>
__global__ __launch_bounds__(256) void attn_mfma_kernel(
    const short* __restrict__ qkv, short* __restrict__ out, int N,
    float* __restrict__ accp, float* __restrict__ mlp) {
    int h = blockIdx.y, b = blockIdx.z;
    int tid = threadIdx.x;
    int lane = tid & 63, wid = tid >> 6;
    int l15 = lane & 15, lhi = lane >> 4;
    __shared__ __align__(16) short smem[2][2048];

    const short* base = qkv + (size_t)b * N * 384;
    int qt = SPLIT ? (blockIdx.x >> 1) : blockIdx.x;
    int half = SPLIT ? (blockIdx.x & 1) : 0;

    int q0w = qt * 64 + wid * 16;
    int qi = q0w + l15;
    int qc = qi < N ? qi : N - 1;
    bf16x8 qf = *(const bf16x8*)(base + (size_t)qc * 384 + h * 16 + (lhi & 1) * 8);
    if (lhi >= 2) qf = bf16x8{0, 0, 0, 0, 0, 0, 0, 0};

    bool isK = (wid < 2);
    int r64 = ((wid & 1) << 5) | (lane >> 1);
    int hb = lane & 1;
    int t_ = r64 >> 4, rr = r64 & 15;
    int gp = ((t_ >> 1) << 5) | ((rr >> 2) << 3) | ((t_ & 1) << 2) | (rr & 3);
    int grow = isK ? gp : r64;
    int soff = (isK ? 128 : 256) + h * 16 + hb * 8;
    int ldsWaveOff = (isK ? 0 : 2048) + ((wid & 1) << 10);

    f32x4 acc = f32x4{0.f, 0.f, 0.f, 0.f};
    float mrun = -1e30f, lrun = 0.f;
    int nktT = (N + 63) >> 6;
    int lo = SPLIT ? half * (nktT >> 1) : 0;
    int hi = SPLIT ? (half ? nktT : (nktT >> 1)) : nktT;

#define STAGE(KT, BUFI) do {                                                        \
        int row_ = (KT) * 64 + grow;                                                \
        row_ = row_ < N ? row_ : N - 1;                                             \
        __builtin_amdgcn_global_load_lds(                                           \
            (const __attribute__((address_space(1))) void*)(base + (size_t)row_ * 384 + soff), \
            (__attribute__((address_space(3))) void*)((char*)&smem[BUFI][0] + ldsWaveOff), 16, 0, 0); \
    } while (0)

    STAGE(lo, 0);
    for (int kt = lo; kt < hi; ++kt) {
        int bf = (kt - lo) & 1;
        if (kt + 1 < hi) {
            STAGE(kt + 1, bf ^ 1);
            asm volatile("s_waitcnt vmcnt(1)" ::: "memory");
        } else {
            asm volatile("s_waitcnt vmcnt(0)" ::: "memory");
        }
        __builtin_amdgcn_s_barrier();
        asm volatile("" ::: "memory");

        const short* kb = smem[bf];
        const short* vb = kb + 1024;

        f32x4 s4[4];
        __builtin_amdgcn_s_setprio(1);
        #pragma unroll
        for (int t = 0; t < 4; ++t) {
            bf16x8 kf = *(const bf16x8*)(kb + (t * 16 + l15) * 16 + (lhi & 1) * 8);
            s4[t] = __builtin_amdgcn_mfma_f32_16x16x32_bf16(kf, qf, f32x4{0.f, 0.f, 0.f, 0.f}, 0, 0, 0);
        }
        __builtin_amdgcn_s_setprio(0);

        int kv0 = kt * 64;
        bool tail = (kv0 + 64 > N);
        float pvv[4][4];
        float mx = -1e30f;
        #pragma unroll
        for (int t = 0; t < 4; ++t)
            #pragma unroll
            for (int r = 0; r < 4; ++r) {
                float v = s4[t][r];
                if (tail) {
                    int kvg = ((t >> 1) << 5) | (lhi << 3) | ((t & 1) << 2) | r;
                    if (kv0 + kvg >= N) v = -1e30f;
                }
                pvv[t][r] = v;
                mx = fmaxf(mx, v);
            }
        mx = fmaxf(mx, __shfl_xor(mx, 16));
        mx = fmaxf(mx, __shfl_xor(mx, 32));
        if (!__all(mx - mrun <= 8.0f)) {            // defer-max (T13)
            float mnew = fmaxf(mrun, mx);
            float fr = __expf(mrun - mnew);
            mrun = mnew;
            lrun *= fr;
            acc[0] *= fr; acc[1] *= fr; acc[2] *= fr; acc[3] *= fr;
        }
        float psum = 0.f;
        #pragma unroll
        for (int t = 0; t < 4; ++t)
            #pragma unroll
            for (int r = 0; r < 4; ++r) {
                float pp = __expf(pvv[t][r] - mrun);
                pvv[t][r] = pp;
                psum += pp;
            }
        lrun += psum;

        union { bf16x8 v8; unsigned u[4]; } pa0u, pa1u;
        pa0u.u[0] = cvtpk(pvv[0][0], pvv[0][1]);
        pa0u.u[1] = cvtpk(pvv[0][2], pvv[0][3]);
        pa0u.u[2] = cvtpk(pvv[1][0], pvv[1][1]);
        pa0u.u[3] = cvtpk(pvv[1][2], pvv[1][3]);
        pa1u.u[0] = cvtpk(pvv[2][0], pvv[2][1]);
        pa1u.u[1] = cvtpk(pvv[2][2], pvv[2][3]);
        pa1u.u[2] = cvtpk(pvv[3][0], pvv[3][1]);
        pa1u.u[3] = cvtpk(pvv[3][2], pvv[3][3]);

        bf16x8 vf0, vf1;
        #pragma unroll
        for (int i2 = 0; i2 < 8; ++i2) {
            vf0[i2] = vb[(lhi * 8 + i2) * 16 + l15];
            vf1[i2] = vb[(32 + lhi * 8 + i2) * 16 + l15];
        }
        __builtin_amdgcn_s_setprio(1);
        acc = __builtin_amdgcn_mfma_f32_16x16x32_bf16(vf0, pa0u.v8, acc, 0, 0, 0);
        acc = __builtin_amdgcn_mfma_f32_16x16x32_bf16(vf1, pa1u.v8, acc, 0, 0, 0);
        __builtin_amdgcn_s_setprio(0);

        asm volatile("s_waitcnt lgkmcnt(0)" ::: "memory");
        __builtin_amdgcn_s_barrier();
        asm volatile("" ::: "memory");
    }
#undef STAGE

    lrun += __shfl_xor(lrun, 16);
    lrun += __shfl_xor(lrun, 32);
    if (SPLIT) {
        if (qi < N) {
            size_t row = (size_t)b * N + qi;
            *(f32x4*)(accp + ((size_t)half * B_ * G_ + row) * 128 + h * 16 + lhi * 4) = acc;
            if (lhi == 0) {
                float* mlq = mlp + ((size_t)half * B_ * G_ + row) * 16 + h * 2;
                mlq[0] = mrun;
                mlq[1] = lrun;
            }
        }
    } else {
        float inv = 1.0f / lrun;
        s16x4 o;
        #pragma unroll
        for (int r = 0; r < 4; ++r) o[r] = f2b(acc[r] * inv);
        if (qi < N)
            *(s16x4*)(out + ((size_t)b * N + qi) * D_ + h * 16 + lhi * 4) = o;
    }
}

// ---------------------------------------------------------------------------
// Combine the two kv-half partials: out = sum(w_i * acc_i) / sum(w_i * l_i)
// ---------------------------------------------------------------------------
__global__ void attn_combine_kernel(const float* __restrict__ accp, const float* __restrict__ mlp,
                                    short* __restrict__ out) {
    int row = blockIdx.x;          // 0 .. B*G-1
    int t = threadIdx.x;           // 0 .. 127
    int h = t >> 4;
    const float* ml0 = mlp + (size_t)row * 16 + h * 2;
    const float* ml1 = mlp + ((size_t)B_ * G_ + row) * 16 + h * 2;
    float m0 = ml0[0], l0 = ml0[1];
    float m1 = ml1[0], l1 = ml1[1];
    float M = fmaxf(m0, m1);
    float w0 = __expf(m0 - M), w1 = __expf(m1 - M);
    float denom = w0 * l0 + w1 * l1;
    float a0 = accp[(size_t)row * 128 + t];
    float a1 = accp[((size_t)B_ * G_ + row) * 128 + t];
    out[(size_t)row * 128 + t] = f2b((w0 * a0 + w1 * a1) / denom);
}

// ---------------------------------------------------------------------------
__global__ void cls_copy_kernel(const short* __restrict__ latent, float* __restrict__ outc) {
    int t = blockIdx.x * 128 + threadIdx.x;
    int b = t >> 7, d = t & 127;
    outc[t] = b2f(latent[(size_t)b * NENC_ * D_ + d]);
}

__global__ void loss_fin_kernel(const float* __restrict__ bs, float* __restrict__ out0) {
    int t = threadIdx.x;   // 64
    float s = bs[t];
    #pragma unroll
    for (int o = 1; o < 64; o <<= 1) s += __shfl_xor(s, o);
    if (t == 0) out0[0] = s * (1.0f / 6144.0f);
}

// ---------------------------------------------------------------------------
extern "C" void kernel_launch(void* const* d_in, const int* in_sizes, int n_in,
                              void* d_out, int out_size, void* d_ws, size_t ws_size,
                              hipStream_t stream) {
    const float* x     = (const float*)d_in[0];
    const float* noise = (const float*)d_in[1];
    const float* pos   = (const float*)d_in[2];
    const float* cls   = (const float*)d_in[3];
    const float* eew   = (const float*)d_in[4];
    const float* eeb   = (const float*)d_in[5];
    const float* nw    = (const float*)d_in[6];
    const float* nb    = (const float*)d_in[7];
    const float* dew   = (const float*)d_in[8];
    const float* deb   = (const float*)d_in[9];
    const float* mtok  = (const float*)d_in[10];
    const float* dnw   = (const float*)d_in[11];
    const float* dnb   = (const float*)d_in[12];
    const float* pw    = (const float*)d_in[13];
    const float* pb    = (const float*)d_in[14];
    const float* eln1w = (const float*)d_in[15];
    const float* eln1b = (const float*)d_in[16];
    const float* eqkvw = (const float*)d_in[17];
    const float* eqkvb = (const float*)d_in[18];
    const float* eprjw = (const float*)d_in[19];
    const float* eprjb = (const float*)d_in[20];
    const float* eln2w = (const float*)d_in[21];
    const float* eln2b = (const float*)d_in[22];
    const float* ef1w  = (const float*)d_in[23];
    const float* ef1b  = (const float*)d_in[24];
    const float* ef2w  = (const float*)d_in[25];
    const float* ef2b  = (const float*)d_in[26];
    const float* dln1w = (const float*)d_in[27];
    const float* dln1b = (const float*)d_in[28];
    const float* dqkvw = (const float*)d_in[29];
    const float* dqkvb = (const float*)d_in[30];
    const float* dprjw = (const float*)d_in[31];
    const float* dprjb = (const float*)d_in[32];
    const float* dln2w = (const float*)d_in[33];
    const float* dln2b = (const float*)d_in[34];
    const float* df1w  = (const float*)d_in[35];
    const float* df1b  = (const float*)d_in[36];
    const float* df2w  = (const float*)d_in[37];
    const float* df2b  = (const float*)d_in[38];

    char* ws = (char*)d_ws;
    int*   rank    = (int*)(ws + 0);              // 32768
    int*   keep    = (int*)(ws + 32768);          // 8192
    float* bsums   = (float*)(ws + 40960);        // 8192
    float* enc_x   = (float*)(ws + 49152);        // 1050624
    float* decx    = (float*)(ws + 1099776);      // 4194304
    short* qkvb16  = (short*)(ws + 5294080);      // 6291456
    short* attnb16 = (short*)(ws + 11585536);     // 2097152
    short* lnb16   = (short*)(ws + 13682688);     // 2097152   (reused as mlp during dec attn)
    short* gelub16 = (short*)(ws + 15779840);     // 8388608   (reused as accp during dec attn)
    short* latb16  = (short*)(ws + 24168448);     // 557056
    float* demb    = (float*)(ws + 24725504);     // 1050624
    short* eqkvT   = (short*)(ws + 25776128);     // 589824
    short* eprjT   = (short*)(ws + 26365952);     // 196608
    short* ef1T    = (short*)(ws + 26562560);     // 786432
    short* ef2T    = (short*)(ws + 27348992);     // 786432
    short* dqkvT   = (short*)(ws + 28135424);     // 196608
    short* dprjT   = (short*)(ws + 28332032);     // 65536
    short* df1T    = (short*)(ws + 28397568);     // 262144
    short* df2T    = (short*)(ws + 28659712);     // 262144
    short* dembT   = (short*)(ws + 28921856);     // 32768

    float* accp = (float*)gelub16;   // 2*8192*128*4 = 8388608 B  (dead during dec attn)
    float* mlp  = (float*)lnb16;     // 2*8192*16*4  = 1048576 B  (dead during dec attn)

    float* outp = (float*)d_out;
    float* pred_out = outp + 1;
    float* mask_out = outp + 1 + B_ * G_;
    float* cls_out  = outp + 1 + 2 * B_ * G_;

#define NIL nullptr, nullptr, nullptr, nullptr, nullptr, nullptr, nullptr, nullptr, nullptr

    prep_kernel<<<dim3(16, 16, 33), 256, 0, stream>>>(
        eqkvw, eprjw, ef1w, ef2w, dqkvw, dprjw, df1w, df2w, dew,
        eqkvT, eprjT, ef1T, ef2T, dqkvT, dprjT, df1T, df2T, dembT);

    rank_kernel<<<dim3(G_ / 256, B_), 256, 0, stream>>>(noise, rank, keep, mask_out);
    embed_ln_kernel<<<dim3(NENC_, B_), 128, 0, stream>>>(x, pos, cls, eew, eeb, keep,
                                                         eln1w, eln1b, enc_x, lnb16);

    const int Menc = B_ * NENC_;                 // 2052
    const int gmE = (Menc + 127) / 128;          // 17
    for (int L = 0; L < 6; ++L) {
        gemm_mfma_kernel<3><<<dim3(gmE, 3), 256, 0, stream>>>(lnb16, eqkvT + (size_t)L * 384 * 128,
            eqkvb + L * 384, nullptr, qkvb16, Menc, 128, 384, NIL);
        attn_mfma_kernel<0><<<dim3((NENC_ + 63) / 64, NH_, B_), 256, 0, stream>>>(
            qkvb16, attnb16, NENC_, nullptr, nullptr);
        gemm_mfma_kernel<4><<<dim3(gmE, 1), 256, 0, stream>>>(attnb16, eprjT + (size_t)L * 128 * 128,
            eprjb + L * D_, enc_x, enc_x, Menc, 128, 128,
            eln2w + L * D_, eln2b + L * D_, lnb16, nullptr, nullptr, nullptr, nullptr, nullptr, nullptr);
        gemm_mfma_kernel<1><<<dim3(gmE, 4), 256, 0, stream>>>(lnb16, ef1T + (size_t)L * 512 * 128,
            ef1b + L * HID_, nullptr, gelub16, Menc, 128, 512, NIL);
        if (L < 5) {
            gemm_mfma_kernel<4><<<dim3(gmE, 1), 256, 0, stream>>>(gelub16, ef2T + (size_t)L * 128 * 512,
                ef2b + L * D_, enc_x, enc_x, Menc, 512, 128,
                eln1w + (L + 1) * D_, eln1b + (L + 1) * D_, lnb16, nullptr, nullptr, nullptr, nullptr, nullptr, nullptr);
        } else {
            gemm_mfma_kernel<5><<<dim3(gmE, 1), 256, 0, stream>>>(gelub16, ef2T + (size_t)L * 128 * 512,
                ef2b + L * D_, enc_x, enc_x, Menc, 512, 128,
                nw, nb, latb16, nullptr, nullptr, nullptr, nullptr, nullptr, nullptr);
        }
    }
    cls_copy_kernel<<<4, 128, 0, stream>>>(latb16, cls_out);

    gemm_mfma_kernel<0><<<dim3(gmE, 1), 256, 0, stream>>>(latb16, dembT, deb, nullptr, demb,
                                                          Menc, 128, 128, NIL);
    decbuild_ln_kernel<<<dim3(G_, B_), 128, 0, stream>>>(demb, mtok, pos, rank,
                                                         dln1w, dln1b, decx, lnb16);

    const int Mdec = B_ * G_;                    // 8192
    const int gmD = Mdec / 128;                  // 64
    for (int L = 0; L < 2; ++L) {
        gemm_mfma_kernel<3><<<dim3(gmD, 3), 256, 0, stream>>>(lnb16, dqkvT + (size_t)L * 384 * 128,
            dqkvb + L * 384, nullptr, qkvb16, Mdec, 128, 384, NIL);
        attn_mfma_kernel<1><<<dim3(2 * (G_ / 64), NH_, B_), 256, 0, stream>>>(
            qkvb16, nullptr, G_, accp, mlp);
        attn_combine_kernel<<<Mdec, 128, 0, stream>>>(accp, mlp, attnb16);
        gemm_mfma_kernel<4><<<dim3(gmD, 1), 256, 0, stream>>>(attnb16, dprjT + (size_t)L * 128 * 128,
            dprjb + L * D_, decx, decx, Mdec, 128, 128,
            dln2w + L * D_, dln2b + L * D_, lnb16, nullptr, nullptr, nullptr, nullptr, nullptr, nullptr);
        gemm_mfma_kernel<1><<<dim3(gmD, 4), 256, 0, stream>>>(lnb16, df1T + (size_t)L * 512 * 128,
            df1b + L * HID_, nullptr, gelub16, Mdec, 128, 512, NIL);
        if (L == 0) {
            gemm_mfma_kernel<4><<<dim3(gmD, 1), 256, 0, stream>>>(gelub16, df2T + (size_t)L * 128 * 512,
                df2b + L * D_, decx, decx, Mdec, 512, 128,
                dln1w + D_, dln1b + D_, lnb16, nullptr, nullptr, nullptr, nullptr, nullptr, nullptr);
        } else {
            gemm_mfma_kernel<6><<<dim3(gmD, 1), 256, 0, stream>>>(gelub16, df2T + (size_t)L * 128 * 512,
                df2b + L * D_, decx, decx, Mdec, 512, 128,
                dnw, dnb, nullptr, pw, pb, x, rank, pred_out, bsums);
        }
    }

    loss_fin_kernel<<<1, 64, 0, stream>>>(bsums, outp);
#undef NIL
}